// Round 22
// 175.953 us; speedup vs baseline: 2.0120x; 1.0411x over previous
//
#include <hip/hip_runtime.h>
#include <hip/hip_bf16.h>

// Problem constants
#define DMODEL 1024
#define DIN    2048
#define NH     32
#define HD     64
#define DS     64
#define LSEQ   1024
#define BB     2
#define DTOT   5312           // 2*DIN + 2*64 + 32 + 1024 + 32
#define ROWS   (BB*LSEQ)      // 2048
// column offsets inside zxbcdt
#define OFF_Z   0
#define OFF_X   2048
#define OFF_BR  4096
#define OFF_CR  4160
#define OFF_DT  4224
#define OFF_TH  4256
#define OFF_LAM 5280
#define NZX     4096          // z+x columns: single-pass bf16 MFMA
#define NREM    (DTOT - NZX)  // 1216 cols: 3-pass split-bf16 MFMA
// segmented scan
#define NSEG 8
#define SEG  (LSEQ / NSEG)    // 128

typedef short  s16x8 __attribute__((ext_vector_type(8)));
typedef float  f32x4 __attribute__((ext_vector_type(4)));
typedef unsigned short u16;

__device__ __forceinline__ unsigned int f2bf(float f) {   // RNE f32->bf16 (finite inputs)
    unsigned int u = __float_as_uint(f);
    u += 0x7fffu + ((u >> 16) & 1u);
    return u >> 16;
}
__device__ __forceinline__ unsigned int pk(float x, float y) {
    return f2bf(x) | (f2bf(y) << 16);
}
__device__ __forceinline__ void split1(float v, u16& hi, u16& lo) {
    const unsigned int h = f2bf(v);
    hi = (u16)h;
    lo = (u16)f2bf(v - __uint_as_float(h << 16));
}
__device__ __forceinline__ void split8(const float4 a, const float4 b,
                                       s16x8& hi, s16x8& lo) {
    u16 h_, l_;
    split1(a.x, h_, l_); hi[0] = (short)h_; lo[0] = (short)l_;
    split1(a.y, h_, l_); hi[1] = (short)h_; lo[1] = (short)l_;
    split1(a.z, h_, l_); hi[2] = (short)h_; lo[2] = (short)l_;
    split1(a.w, h_, l_); hi[3] = (short)h_; lo[3] = (short)l_;
    split1(b.x, h_, l_); hi[4] = (short)h_; lo[4] = (short)l_;
    split1(b.y, h_, l_); hi[5] = (short)h_; lo[5] = (short)l_;
    split1(b.z, h_, l_); hi[6] = (short)h_; lo[6] = (short)l_;
    split1(b.w, h_, l_); hi[7] = (short)h_; lo[7] = (short)l_;
}
__device__ __forceinline__ void cvt8(const float4 a, const float4 b, s16x8& hi) {
    hi[0] = (short)f2bf(a.x); hi[1] = (short)f2bf(a.y);
    hi[2] = (short)f2bf(a.z); hi[3] = (short)f2bf(a.w);
    hi[4] = (short)f2bf(b.x); hi[5] = (short)f2bf(b.y);
    hi[6] = (short)f2bf(b.z); hi[7] = (short)f2bf(b.w);
}

// HBM -> LDS direct 16B copy. Dest = wave-uniform base + lane*16 (m104).
typedef const __attribute__((address_space(1))) unsigned int glb_u32;
typedef __attribute__((address_space(3))) unsigned int lds_u32;
__device__ __forceinline__ void gload16(const void* g, void* l) {
    __builtin_amdgcn_global_load_lds((glb_u32*)g, (lds_u32*)l, 16, 0, 0);
}

// XOR swizzles (involutions; source chunk + LDS read index; rule #21).
#define SWZ(row)  (((row) >> 1) & 3)   // 4 chunks/row  (BK=32 tiles)
#define SWZ8(row) (((row) >> 1) & 7)   // 8 chunks/row  (BK=64 tiles)

// ---------------------------------------------------------------------------
// merged conversion kernel: u (blocks 0..2047) and in_proj_w (rest).
// ---------------------------------------------------------------------------
#define CONV_U_BLOCKS (ROWS * DMODEL / 4 / 256)           // 2048
#define CONV_W_BLOCKS ((DTOT * DMODEL / 4) / 256)         // 5312
__global__ __launch_bounds__(256) void conv_uw(const float* __restrict__ usrc,
        const float* __restrict__ wsrc, u16* __restrict__ u_hi,
        u16* __restrict__ u_lo, u16* __restrict__ w_hi, u16* __restrict__ w_lo) {
    const int bid = blockIdx.x;
    if (bid < CONV_U_BLOCKS) {
        const size_t i4 = ((size_t)bid * 256 + threadIdx.x) * 4;
        const float4 v = *(const float4*)(usrc + i4);
        const unsigned int h0 = f2bf(v.x), h1 = f2bf(v.y), h2 = f2bf(v.z), h3 = f2bf(v.w);
        uint2 hw, lw;
        hw.x = h0 | (h1 << 16); hw.y = h2 | (h3 << 16);
        lw.x = pk(v.x - __uint_as_float(h0 << 16), v.y - __uint_as_float(h1 << 16));
        lw.y = pk(v.z - __uint_as_float(h2 << 16), v.w - __uint_as_float(h3 << 16));
        *(uint2*)(u_hi + i4) = hw;
        *(uint2*)(u_lo + i4) = lw;
    } else {
        const size_t i4 = ((size_t)(bid - CONV_U_BLOCKS) * 256 + threadIdx.x) * 4;
        const float4 v = *(const float4*)(wsrc + i4);
        const unsigned int h0 = f2bf(v.x), h1 = f2bf(v.y), h2 = f2bf(v.z), h3 = f2bf(v.w);
        uint2 hw, lw;
        hw.x = h0 | (h1 << 16); hw.y = h2 | (h3 << 16);
        lw.x = pk(v.x - __uint_as_float(h0 << 16), v.y - __uint_as_float(h1 << 16));
        lw.y = pk(v.z - __uint_as_float(h2 << 16), v.w - __uint_as_float(h3 << 16));
        *(uint2*)(w_hi + i4) = hw;
        if ((i4 >> 10) >= NZX)
            *(uint2*)(w_lo + (i4 - (size_t)NZX * DMODEL)) = lw;
    }
}

// ---------------------------------------------------------------------------
// merged in_proj GEMM: blocks 0..511 = z/x tiles (BK=64, single barrier per
// K-tile); blocks 512..815 = rem3 split-bf16 tiles (BK=32, 3-pass).
// Independent outputs (zx cols 0..4095 vs 4096..5311); union LDS 64KB ->
// 2 blocks/CU in both branches. Bodies identical to the two proven kernels.
// ---------------------------------------------------------------------------
#define ZX_BLOCKS 512
#define R3_BLOCKS ((NREM / 64) * (ROWS / 128))   // 19*16 = 304
__global__ __launch_bounds__(256) void mfma_inproj(const u16* __restrict__ u_bf,
        const u16* __restrict__ u_lo, const u16* __restrict__ w_bf,
        const u16* __restrict__ w_lo, float* __restrict__ zx) {
    __shared__ u16 smem[32768];    // 64 KB union
    const int tid = threadIdx.x;
    const int lane = tid & 63, wave = tid >> 6;
    const int wr = wave >> 1, wc = wave & 1;
    const int lr = lane >> 4, lc = lane & 15;

    if (blockIdx.x < ZX_BLOCKS) {
        // ---------------- z/x branch (BK=64) ----------------
        const int bid = blockIdx.x;
        const int m0 = (bid >> 5) * 128, n0 = (bid & 31) * 128;
        const int sr = tid >> 3;
        const int sc = (((tid & 7) ^ ((tid >> 4) & 7)) * 8);
        f32x4 acc[4][4] = {};
        const u16* pA = u_bf + (size_t)(m0 + sr) * DMODEL + sc;
        const u16* pB = w_bf + (size_t)(n0 + sr) * DMODEL + sc;
        u16* Al = smem;              // buf stride 8192 u16
        u16* Bl = smem + 16384;

#define STAGE_ZX(buf, k0) {                                                       \
        gload16(pA + (k0),                       Al + (buf)*8192 + tid*8);        \
        gload16(pA + (k0) + (size_t)32 * DMODEL, Al + (buf)*8192 + tid*8 + 2048); \
        gload16(pA + (k0) + (size_t)64 * DMODEL, Al + (buf)*8192 + tid*8 + 4096); \
        gload16(pA + (k0) + (size_t)96 * DMODEL, Al + (buf)*8192 + tid*8 + 6144); \
        gload16(pB + (k0),                       Bl + (buf)*8192 + tid*8);        \
        gload16(pB + (k0) + (size_t)32 * DMODEL, Bl + (buf)*8192 + tid*8 + 2048); \
        gload16(pB + (k0) + (size_t)64 * DMODEL, Bl + (buf)*8192 + tid*8 + 4096); \
        gload16(pB + (k0) + (size_t)96 * DMODEL, Bl + (buf)*8192 + tid*8 + 6144); }

        STAGE_ZX(0, 0);
        __syncthreads();
        int cur = 0;
        for (int k0 = 0; k0 < DMODEL; k0 += 64) {
            if (k0 + 64 < DMODEL) STAGE_ZX(cur ^ 1, k0 + 64);
            #pragma unroll
            for (int kk = 0; kk < 2; ++kk) {
                s16x8 af[4], bf[4];
                #pragma unroll
                for (int f = 0; f < 4; ++f) {
                    const int ra = wr * 64 + f * 16 + lc;
                    af[f] = *(const s16x8*)&Al[cur * 8192 + ra * 64 + (((kk * 4 + lr) ^ SWZ8(ra)) * 8)];
                    const int rb = wc * 64 + f * 16 + lc;
                    bf[f] = *(const s16x8*)&Bl[cur * 8192 + rb * 64 + (((kk * 4 + lr) ^ SWZ8(rb)) * 8)];
                }
                #pragma unroll
                for (int fm = 0; fm < 4; ++fm)
                    #pragma unroll
                    for (int fn = 0; fn < 4; ++fn)
                        acc[fm][fn] = __builtin_amdgcn_mfma_f32_16x16x32_bf16(
                            af[fm], bf[fn], acc[fm][fn], 0, 0, 0);
            }
            __syncthreads();
            cur ^= 1;
        }
#undef STAGE_ZX

        #pragma unroll
        for (int fm = 0; fm < 4; ++fm)
            #pragma unroll
            for (int fn = 0; fn < 4; ++fn) {
                const size_t col = n0 + wc * 64 + fn * 16 + lc;
                #pragma unroll
                for (int j = 0; j < 4; ++j) {
                    const size_t row = m0 + wr * 64 + fm * 16 + lr * 4 + j;
                    zx[row * DTOT + col] = acc[fm][fn][j];
                }
            }
    } else {
        // ---------------- rem3 branch (BK=32, 3-pass split) ----------------
        const int rid = blockIdx.x - ZX_BLOCKS;
        const int m0 = (rid / (NREM / 64)) * 128, n0 = (rid % (NREM / 64)) * 64;
        const int sr = tid >> 2;
        const int sc = (((tid & 3) ^ SWZ(tid >> 2)) * 8);
        f32x4 acc[4][2] = {};
        const u16* pAh = u_bf + (size_t)(m0 + sr) * DMODEL + sc;
        const u16* pAl = u_lo + (size_t)(m0 + sr) * DMODEL + sc;
        const u16* pBh = w_bf + (size_t)(NZX + n0 + sr) * DMODEL + sc;
        const u16* pBl = w_lo + (size_t)(n0 + sr) * DMODEL + sc;
        u16* Ah  = smem;             // buf stride 4096 u16
        u16* Alo = smem + 8192;
        u16* Bh  = smem + 16384;     // buf stride 2048 u16
        u16* Blo = smem + 20480;

#define STAGE_R3(buf, k0) {                                                          \
        gload16(pAh + (k0),                       Ah  + (buf)*4096 + tid*8);         \
        gload16(pAh + (k0) + (size_t)64 * DMODEL, Ah  + (buf)*4096 + tid*8 + 2048);  \
        gload16(pAl + (k0),                       Alo + (buf)*4096 + tid*8);         \
        gload16(pAl + (k0) + (size_t)64 * DMODEL, Alo + (buf)*4096 + tid*8 + 2048);  \
        gload16(pBh + (k0),                       Bh  + (buf)*2048 + tid*8);         \
        gload16(pBl + (k0),                       Blo + (buf)*2048 + tid*8); }

        STAGE_R3(0, 0);
        __syncthreads();
        int cur = 0;
        for (int k0 = 0; k0 < DMODEL; k0 += 32) {
            if (k0 + 32 < DMODEL) STAGE_R3(cur ^ 1, k0 + 32);
            s16x8 ahf[4], alf[4], bhf[2], blf[2];
            #pragma unroll
            for (int f = 0; f < 4; ++f) {
                const int ra = wr * 64 + f * 16 + lc;
                const int oa = ra * 32 + ((lr ^ SWZ(ra)) * 8);
                ahf[f] = *(const s16x8*)&Ah[cur * 4096 + oa];
                alf[f] = *(const s16x8*)&Alo[cur * 4096 + oa];
            }
            #pragma unroll
            for (int f = 0; f < 2; ++f) {
                const int rb = wc * 32 + f * 16 + lc;
                const int ob = rb * 32 + ((lr ^ SWZ(rb)) * 8);
                bhf[f] = *(const s16x8*)&Bh[cur * 2048 + ob];
                blf[f] = *(const s16x8*)&Blo[cur * 2048 + ob];
            }
            #pragma unroll
            for (int fm = 0; fm < 4; ++fm)
                #pragma unroll
                for (int fn = 0; fn < 2; ++fn) {
                    acc[fm][fn] = __builtin_amdgcn_mfma_f32_16x16x32_bf16(
                        ahf[fm], bhf[fn], acc[fm][fn], 0, 0, 0);
                    acc[fm][fn] = __builtin_amdgcn_mfma_f32_16x16x32_bf16(
                        ahf[fm], blf[fn], acc[fm][fn], 0, 0, 0);
                    acc[fm][fn] = __builtin_amdgcn_mfma_f32_16x16x32_bf16(
                        alf[fm], bhf[fn], acc[fm][fn], 0, 0, 0);
                }
            __syncthreads();
            cur ^= 1;
        }
#undef STAGE_R3

        #pragma unroll
        for (int fm = 0; fm < 4; ++fm)
            #pragma unroll
            for (int fn = 0; fn < 2; ++fn) {
                const size_t col = NZX + n0 + wc * 32 + fn * 16 + lc;
                #pragma unroll
                for (int j = 0; j < 4; ++j) {
                    const size_t row = m0 + wr * 64 + fm * 16 + lr * 4 + j;
                    zx[row * DTOT + col] = acc[fm][fn][j];
                }
            }
    }
}

// ---------------------------------------------------------------------------
// bf16 MFMA GEMM, 128x64 tile, BK=64: out = gn_bf @ wo_bf^T (LDS 48KB)
// ---------------------------------------------------------------------------
__global__ __launch_bounds__(256) void mfma_gemm_out(const u16* __restrict__ A,
                                                     const u16* __restrict__ B,
                                                     float* __restrict__ C,
                                                     int K, int ldc) {
    __shared__ u16 Als[2][128 * 64];
    __shared__ u16 Bls[2][64 * 64];
    const int tid = threadIdx.x;
    const int m0 = blockIdx.y * 128, n0 = blockIdx.x * 64;
    const int lane = tid & 63, wave = tid >> 6;
    const int wr = wave >> 1, wc = wave & 1;
    const int lr = lane >> 4, lc = lane & 15;
    const int sr = tid >> 3;
    const int sc = (((tid & 7) ^ ((tid >> 4) & 7)) * 8);

    f32x4 acc[4][2] = {};

    const u16* pA = A + (size_t)(m0 + sr) * K + sc;
    const u16* pB = B + (size_t)(n0 + sr) * K + sc;

#define STAGE_OUT(buf, k0) {                                                  \
        gload16(pA + (k0),                   &Als[buf][tid * 8]);             \
        gload16(pA + (k0) + (size_t)32 * K,  &Als[buf][tid * 8 + 2048]);      \
        gload16(pA + (k0) + (size_t)64 * K,  &Als[buf][tid * 8 + 4096]);      \
        gload16(pA + (k0) + (size_t)96 * K,  &Als[buf][tid * 8 + 6144]);      \
        gload16(pB + (k0),                   &Bls[buf][tid * 8]);             \
        gload16(pB + (k0) + (size_t)32 * K,  &Bls[buf][tid * 8 + 2048]); }

    STAGE_OUT(0, 0);
    __syncthreads();
    int cur = 0;
    for (int k0 = 0; k0 < K; k0 += 64) {
        if (k0 + 64 < K) STAGE_OUT(cur ^ 1, k0 + 64);
        #pragma unroll
        for (int kk = 0; kk < 2; ++kk) {
            s16x8 af[4], bf[2];
            #pragma unroll
            for (int f = 0; f < 4; ++f) {
                const int ra = wr * 64 + f * 16 + lc;
                af[f] = *(const s16x8*)&Als[cur][ra * 64 + (((kk * 4 + lr) ^ SWZ8(ra)) * 8)];
            }
            #pragma unroll
            for (int f = 0; f < 2; ++f) {
                const int rb = wc * 32 + f * 16 + lc;
                bf[f] = *(const s16x8*)&Bls[cur][rb * 64 + (((kk * 4 + lr) ^ SWZ8(rb)) * 8)];
            }
            #pragma unroll
            for (int fm = 0; fm < 4; ++fm)
                #pragma unroll
                for (int fn = 0; fn < 2; ++fn)
                    acc[fm][fn] = __builtin_amdgcn_mfma_f32_16x16x32_bf16(
                        af[fm], bf[fn], acc[fm][fn], 0, 0, 0);
        }
        __syncthreads();
        cur ^= 1;
    }
#undef STAGE_OUT

    #pragma unroll
    for (int fm = 0; fm < 4; ++fm)
        #pragma unroll
        for (int fn = 0; fn < 2; ++fn) {
            const size_t col = n0 + wc * 32 + fn * 16 + lc;
            #pragma unroll
            for (int j = 0; j < 4; ++j) {
                const size_t row = m0 + wr * 64 + fm * 16 + lr * 4 + j;
                C[row * (size_t)ldc + col] = acc[fm][fn][j];
            }
        }
}

// ---------------------------------------------------------------------------
// merged prep + cumsum (both only READ zx; outputs disjoint -> race-free).
// ---------------------------------------------------------------------------
__global__ __launch_bounds__(256) void prep_cumsum(const float* __restrict__ zx,
        const float* __restrict__ dt_bias, const float* __restrict__ A_log,
        const float* __restrict__ B_norm_w, const float* __restrict__ C_norm_w,
        float* __restrict__ Bg, float* __restrict__ Cg,
        float4* __restrict__ abg4, float* __restrict__ th_cs) {
    __shared__ float sums[8][33];
    const int bid = blockIdx.x;
    const int tid = threadIdx.x;
    if (bid < 512) {
        const int bl = bid * 4 + (tid >> 6);
        const int t  = tid & 63;
        const int b = bl >> 10, l = bl & (LSEQ - 1);
        const float* row = zx + (size_t)bl * DTOT;
        const float br = row[OFF_BR + t];
        const float cr = row[OFF_CR + t];
        float ssb = br * br, ssc = cr * cr;
        #pragma unroll
        for (int k = 1; k < 64; k <<= 1) { ssb += __shfl_xor(ssb, k); ssc += __shfl_xor(ssc, k); }
        const float scB = rsqrtf(ssb * (1.f / 64.f) + 1e-5f);
        const float scC = rsqrtf(ssc * (1.f / 64.f) + 1e-5f);
        Bg[(size_t)bl * 64 + t] = br * scB * B_norm_w[t];
        Cg[(size_t)bl * 64 + t] = cr * scC * C_norm_w[t];
        if (t < NH) {
            const float dtr = row[OFF_DT + t] + dt_bias[t];
            const float dt  = (dtr > 20.f) ? dtr : log1pf(expf(dtr));
            const float lamr = row[OFF_LAM + t];
            const float lam  = 1.f / (1.f + expf(-lamr));
            const float Ah   = -expf(A_log[t]);
            const float al   = expf(dt * Ah);
            const float bp   = (1.f - lam) * dt;        // beta' = b/a
            const size_t o = ((size_t)b * NH + t) * LSEQ + l;
            abg4[o] = make_float4(al, bp * al, lam * dt, bp);
        }
    } else {
        const int bh = bid - 512;
        const int b = bh >> 5, h = bh & 31;
        const int d = tid & 31, seg = tid >> 5;
        const float* base = zx + (size_t)b * LSEQ * DTOT + OFF_TH + h * 32 + d;
        float* out = th_cs + (size_t)b * LSEQ * 1024 + h * 32 + d;
        const int l0 = seg * 128;
        float s = 0.f;
        #pragma unroll 4
        for (int i = 0; i < 128; ++i) s += base[(size_t)(l0 + i) * DTOT];
        sums[seg][d] = s;
        __syncthreads();
        float acc = 0.f;
        for (int s2 = 0; s2 < seg; ++s2) acc += sums[s2][d];
        #pragma unroll 4
        for (int i = 0; i < 128; ++i) {
            acc += base[(size_t)(l0 + i) * DTOT];
            out[(size_t)(l0 + i) * 1024] = acc;
        }
    }
}

// ---------------------------------------------------------------------------
// rot: Bh/Ch = rot(broadcast(Bg/Cg)+bias). Brot/Crot layout (B,NH,L,DS).
// ---------------------------------------------------------------------------
__global__ __launch_bounds__(256) void rot_kernel(const float* __restrict__ th_cs,
        const float* __restrict__ Bg, const float* __restrict__ Cg,
        const float* __restrict__ B_bias, const float* __restrict__ C_bias,
        float* __restrict__ Brot, float* __restrict__ Crot) {
    const size_t idx = (size_t)blockIdx.x * 256 + threadIdx.x;
    const int j = (int)(idx & 31);
    const int h = (int)((idx >> 5) & 31);
    const size_t bl = idx >> 10;
    const int l = (int)(bl & (LSEQ - 1));
    const int b = (int)(bl >> 10);
    const float th = th_cs[idx];
    float s, c;
    sincosf(th, &s, &c);
    float v1 = Bg[bl * 64 + j]      + B_bias[h * 64 + j];
    float v2 = Bg[bl * 64 + 32 + j] + B_bias[h * 64 + 32 + j];
    const size_t ob = ((size_t)(b * NH + h) * LSEQ + l) * DS + j;
    Brot[ob]      = v1 * c - v2 * s;
    Brot[ob + 32] = v1 * s + v2 * c;
    v1 = Cg[bl * 64 + j]      + C_bias[h * 64 + j];
    v2 = Cg[bl * 64 + 32 + j] + C_bias[h * 64 + 32 + j];
    Crot[ob]      = v1 * c - v2 * s;
    Crot[ob + 32] = v1 * s + v2 * c;
}

// ---------------------------------------------------------------------------
// wcalc: per (b,h,seg): within-seg log-cumsum of alpha; emits
//   wbuf[t], Lbuf[t], aprod[s], bscale[s]  (round 13/15 derivation)
// ---------------------------------------------------------------------------
__global__ __launch_bounds__(64) void wcalc_kernel(const float4* __restrict__ abg4,
        float* __restrict__ wbuf, float* __restrict__ aprod,
        float* __restrict__ bscale, float* __restrict__ Lbuf) {
    const int bh = blockIdx.x;
    const int lane = threadIdx.x;
    const int seg = lane >> 3, sub = lane & 7;
    const int t0 = seg * SEG;
    const int sbase = t0 + sub * 16;
    const float4* ab = abg4 + (size_t)bh * LSEQ;

    float part = 0.f;
    #pragma unroll
    for (int i = 0; i < 16; ++i) part += logf(ab[sbase + i].x);
    float incl = part;
    #pragma unroll
    for (int d = 1; d < 8; d <<= 1) {
        const float v = __shfl_up(incl, d, 8);
        if (sub >= d) incl += v;
    }
    const float LE = __shfl(incl, 7, 8);
    float Lrun = incl - part;                // exclusive prefix

    for (int i = 0; i < 16; ++i) {
        const int s = sbase + i;
        const float4 A = ab[s];
        Lrun += logf(A.x);
        Lbuf[(size_t)bh * LSEQ + s] = Lrun;
        float w;
        if ((s & (SEG - 1)) == (SEG - 1)) w = A.z;
        else w = __expf(LE - Lrun) * (A.z + ab[s + 1].w);
        wbuf[(size_t)bh * LSEQ + s] = w;
    }
    if (sub == 0) {
        aprod[bh * NSEG + seg] = __expf(LE);
        bscale[bh * NSEG + seg] = (seg > 0) ? __expf(LE) * ab[t0].w : 0.f;
    }
}

// ---------------------------------------------------------------------------
// hseg_gemm: h_local_end[p,n] = sum_s wbuf_s * x_s[p] * B_s[n] (split-bf16 3-pass)
// ---------------------------------------------------------------------------
#define WK 136
__global__ __launch_bounds__(256) void hseg_gemm(const float* __restrict__ zx,
        const float* __restrict__ Brot, const float* __restrict__ wbuf,
        float* __restrict__ hseg) {
    __shared__ u16 XH[64][WK], XL[64][WK], BHs[64][WK], BLs[64][WK];
    const int blk = blockIdx.x;
    const int seg = blk & (NSEG - 1), bh = blk >> 3;
    const int b = bh >> 5, h = bh & 31;
    const int tid = threadIdx.x;

    {
        const int sIdx = tid >> 1, half = tid & 1;
        const int t = seg * SEG + sIdx;
        const float wv = wbuf[(size_t)bh * LSEQ + t];
        const float* xsrc = zx + ((size_t)b * LSEQ + t) * DTOT + OFF_X + h * 64 + half * 32;
        const float* bsrc = Brot + ((size_t)bh * LSEQ + t) * DS + half * 32;
        #pragma unroll
        for (int i = 0; i < 32; i += 4) {
            const float4 xv = *(const float4*)(xsrc + i);
            const float4 bv = *(const float4*)(bsrc + i);
            const int p0 = half * 32 + i;
            u16 hi, lo;
            split1(xv.x * wv, hi, lo); XH[p0 + 0][sIdx] = hi; XL[p0 + 0][sIdx] = lo;
            split1(xv.y * wv, hi, lo); XH[p0 + 1][sIdx] = hi; XL[p0 + 1][sIdx] = lo;
            split1(xv.z * wv, hi, lo); XH[p0 + 2][sIdx] = hi; XL[p0 + 2][sIdx] = lo;
            split1(xv.w * wv, hi, lo); XH[p0 + 3][sIdx] = hi; XL[p0 + 3][sIdx] = lo;
            split1(bv.x, hi, lo); BHs[p0 + 0][sIdx] = hi; BLs[p0 + 0][sIdx] = lo;
            split1(bv.y, hi, lo); BHs[p0 + 1][sIdx] = hi; BLs[p0 + 1][sIdx] = lo;
            split1(bv.z, hi, lo); BHs[p0 + 2][sIdx] = hi; BLs[p0 + 2][sIdx] = lo;
            split1(bv.w, hi, lo); BHs[p0 + 3][sIdx] = hi; BLs[p0 + 3][sIdx] = lo;
        }
    }
    __syncthreads();

    const int lane = tid & 63, wave = tid >> 6;
    const int wR = wave >> 1, wC = wave & 1;
    const int lr = lane >> 4, lc = lane & 15;

    f32x4 acc[2][2] = {};
    #pragma unroll
    for (int ks = 0; ks < 4; ++ks) {
        const int k0 = ks * 32;
        s16x8 xh[2], xl[2], bhf[2], blf[2];
        #pragma unroll
        for (int f = 0; f < 2; ++f) {
            const int pr = wR * 32 + f * 16 + lc;
            xh[f] = *(const s16x8*)&XH[pr][k0 + lr * 8];
            xl[f] = *(const s16x8*)&XL[pr][k0 + lr * 8];
            const int nr = wC * 32 + f * 16 + lc;
            bhf[f] = *(const s16x8*)&BHs[nr][k0 + lr * 8];
            blf[f] = *(const s16x8*)&BLs[nr][k0 + lr * 8];
        }
        #pragma unroll
        for (int fm = 0; fm < 2; ++fm)
            #pragma unroll
            for (int fn = 0; fn < 2; ++fn) {
                acc[fm][fn] = __builtin_amdgcn_mfma_f32_16x16x32_bf16(
                    xh[fm], bhf[fn], acc[fm][fn], 0, 0, 0);
                acc[fm][fn] = __builtin_amdgcn_mfma_f32_16x16x32_bf16(
                    xh[fm], blf[fn], acc[fm][fn], 0, 0, 0);
                acc[fm][fn] = __builtin_amdgcn_mfma_f32_16x16x32_bf16(
                    xl[fm], bhf[fn], acc[fm][fn], 0, 0, 0);
            }
    }

    float* hp = hseg + ((size_t)(bh * NSEG + seg) * HD) * DS;
    #pragma unroll
    for (int fm = 0; fm < 2; ++fm)
        #pragma unroll
        for (int fn = 0; fn < 2; ++fn) {
            const int n = wC * 32 + fn * 16 + lc;
            #pragma unroll
            for (int j = 0; j < 4; ++j) {
                const int p = wR * 32 + fm * 16 + lr * 4 + j;
                hp[p * DS + n] = acc[fm][fn][j];
            }
        }
}

// ---------------------------------------------------------------------------
// scan_fix: sequential over segments -> hseg becomes hstar per segment.
// ---------------------------------------------------------------------------
__global__ __launch_bounds__(256) void scan_fix(float* __restrict__ hseg,
        const float* __restrict__ aprod, const float* __restrict__ bscale,
        const float* __restrict__ zx, const float* __restrict__ Brot,
        const float4* __restrict__ abg4) {
    const int blk = blockIdx.x;          // (b,h,ptile): 256
    const int ptile = blk & 3, h = (blk >> 2) & 31, b = blk >> 7;
    const int tid = threadIdx.x;
    const int pl = tid >> 4, ng = tid & 15;
    const int p = ptile * 16 + pl;
    const int n0 = ng * 4;
    const size_t bh = (size_t)b * NH + h;

    float4 cur = make_float4(0.f, 0.f, 0.f, 0.f);
    #pragma unroll
    for (int s = 0; s < NSEG; ++s) {
        float* hp = hseg + (((bh * NSEG + s) * HD + p) * DS + n0);
        float4 tmp = *(const float4*)hp;     // local h_end (no boundary)
        float4 hst = cur;                    // hstar = h_start (+ r1 below)
        if (s > 0) {
            const float bs = bscale[bh * NSEG + s];          // aprod*beta'
            const float bp0 = abg4[bh * LSEQ + s * SEG].w;   // beta'_{t0}
            const int tm1 = s * SEG - 1;
            const float4 Bm = *(const float4*)(Brot + ((size_t)bh * LSEQ + tm1) * DS + n0);
            const float xm = zx[((size_t)b * LSEQ + tm1) * DTOT + OFF_X + h * HD + p];
            const float fb = bs * xm;
            const float f1 = bp0 * xm;
            tmp.x = fmaf(fb, Bm.x, tmp.x);
            tmp.y = fmaf(fb, Bm.y, tmp.y);
            tmp.z = fmaf(fb, Bm.z, tmp.z);
            tmp.w = fmaf(fb, Bm.w, tmp.w);
            hst.x = fmaf(f1, Bm.x, hst.x);
            hst.y = fmaf(f1, Bm.y, hst.y);
            hst.z = fmaf(f1, Bm.z, hst.z);
            hst.w = fmaf(f1, Bm.w, hst.w);
        }
        *(float4*)hp = hst;
        const float a = aprod[bh * NSEG + s];
        cur.x = fmaf(a, cur.x, tmp.x);
        cur.y = fmaf(a, cur.y, tmp.y);
        cur.z = fmaf(a, cur.z, tmp.z);
        cur.w = fmaf(a, cur.w, tmp.w);
    }
}

// ---------------------------------------------------------------------------
// ssd_y v3: C/B/H fragments from global (L2); Gw fp32 in LDS with D folded
// into the diagonal; X^T staged in LDS in two 64-step halves. 2 blocks/CU.
// ---------------------------------------------------------------------------
#define GWF 132
#define XTS 72
__global__ __launch_bounds__(256, 2) void ssd_y(const float* __restrict__ zx,
        const float* __restrict__ Brot, const float* __restrict__ Crot,
        const float4* __restrict__ abg4, const float* __restrict__ hseg,
        const float* __restrict__ Lbuf, const float* __restrict__ Dp,
        float* __restrict__ yb) {
    __shared__ float Gw[128 * GWF];
    __shared__ u16 XTh[64 * XTS];
    __shared__ float Ls[128], gbs[128], gms[128], eLs[128];

    const int blk = blockIdx.x;
    const int seg = blk & (NSEG - 1), bh = blk >> 3;
    const int b = bh >> 5, h = bh & 31;
    const int tid = threadIdx.x;
    const int t0 = seg * SEG;
    const int lane = tid & 63, wave = tid >> 6;
    const int wr = wave >> 1, wc = wave & 1;
    const int lr = lane >> 4, lc = lane & 15;

    if (tid < 128) {
        const int t = t0 + tid;
        const float4 A = abg4[(size_t)bh * LSEQ + t];
        const float Lv = Lbuf[(size_t)bh * LSEQ + t];
        Ls[tid] = Lv;
        gms[tid] = A.z;
        gbs[tid] = (tid < 127) ? A.z + abg4[(size_t)bh * LSEQ + t + 1].w : 0.f;
        eLs[tid] = __expf(Lv);
    }
    __syncthreads();

    const float* Cbase = Crot + ((size_t)bh * LSEQ + t0) * DS;
    const float* Bbase = Brot + ((size_t)bh * LSEQ + t0) * DS;
    const float* Hbase = hseg + ((size_t)(bh * NSEG + seg) * HD) * DS;
    const float* Xbase = zx + ((size_t)b * LSEQ + t0) * DTOT + OFF_X + h * 64;

    f32x4 accP[4][2] = {};
    f32x4 accG[4][4] = {};
    #pragma unroll
    for (int ks = 0; ks < 2; ++ks) {
        const int k0 = ks * 32 + lr * 8;
        s16x8 ch[4], cl4[4], bh4[4], bl4[4], hh2[2];
        #pragma unroll
        for (int f = 0; f < 4; ++f) {
            const int rowc = wr * 64 + f * 16 + lc;
            const float4 c0 = *(const float4*)(Cbase + (size_t)rowc * DS + k0);
            const float4 c1 = *(const float4*)(Cbase + (size_t)rowc * DS + k0 + 4);
            split8(c0, c1, ch[f], cl4[f]);
            const int rowb = wc * 64 + f * 16 + lc;
            const float4 b0 = *(const float4*)(Bbase + (size_t)rowb * DS + k0);
            const float4 b1 = *(const float4*)(Bbase + (size_t)rowb * DS + k0 + 4);
            split8(b0, b1, bh4[f], bl4[f]);
        }
        #pragma unroll
        for (int f = 0; f < 2; ++f) {
            const int rowp = wc * 32 + f * 16 + lc;
            const float4 h0 = *(const float4*)(Hbase + (size_t)rowp * DS + k0);
            const float4 h1 = *(const float4*)(Hbase + (size_t)rowp * DS + k0 + 4);
            cvt8(h0, h1, hh2[f]);
        }
        #pragma unroll
        for (int fm = 0; fm < 4; ++fm) {
            #pragma unroll
            for (int fn = 0; fn < 4; ++fn) {
                accG[fm][fn] = __builtin_amdgcn_mfma_f32_16x16x32_bf16(
                    ch[fm], bh4[fn], accG[fm][fn], 0, 0, 0);
                accG[fm][fn] = __builtin_amdgcn_mfma_f32_16x16x32_bf16(
                    ch[fm], bl4[fn], accG[fm][fn], 0, 0, 0);
                accG[fm][fn] = __builtin_amdgcn_mfma_f32_16x16x32_bf16(
                    cl4[fm], bh4[fn], accG[fm][fn], 0, 0, 0);
            }
            #pragma unroll
            for (int fn = 0; fn < 2; ++fn) {
                accP[fm][fn] = __builtin_amdgcn_mfma_f32_16x16x32_bf16(
                    ch[fm], hh2[fn], accP[fm][fn], 0, 0, 0);
                accP[fm][fn] = __builtin_amdgcn_mfma_f32_16x16x32_bf16(
                    cl4[fm], hh2[fn], accP[fm][fn], 0, 0, 0);
            }
        }
    }

    const float Dh = Dp[h];
    #pragma unroll
    for (int fm = 0; fm < 4; ++fm)
        #pragma unroll
        for (int fn = 0; fn < 4; ++fn)
            #pragma unroll
            for (int jj = 0; jj < 4; ++jj) {
                const int i = wr * 64 + fm * 16 + lr * 4 + jj;
                const int j = wc * 64 + fn * 16 + lc;
                float v;
                if (j < i)       v = accG[fm][fn][jj] * __expf(Ls[i] - Ls[j]) * gbs[j];
                else if (j == i) v = accG[fm][fn][jj] * gms[i] + Dh;
                else             v = 0.f;
                Gw[i * GWF + j] = v;
            }

    f32x4 accY[4][2];
    #pragma unroll
    for (int fm = 0; fm < 4; ++fm)
        #pragma unroll
        for (int fn = 0; fn < 2; ++fn)
            #pragma unroll
            for (int jj = 0; jj < 4; ++jj) {
                const int i = wr * 64 + fm * 16 + lr * 4 + jj;
                accY[fm][fn][jj] = eLs[i] * accP[fm][fn][jj];
            }

#define STAGE_XT(H) {                                                        \
        const int lp = tid >> 2, pq = (tid & 3) * 16;                        \
        const float* xs = Xbase + (size_t)((H) * 64 + lp) * DTOT + pq;       \
        _Pragma("unroll")                                                    \
        for (int i = 0; i < 16; i += 4) {                                    \
            const float4 xv = *(const float4*)(xs + i);                      \
            XTh[(pq + i + 0) * XTS + lp] = (u16)f2bf(xv.x);                  \
            XTh[(pq + i + 1) * XTS + lp] = (u16)f2bf(xv.y);                  \
            XTh[(pq + i + 2) * XTS + lp] = (u16)f2bf(xv.z);                  \
            XTh[(pq + i + 3) * XTS + lp] = (u16)f2bf(xv.w);                  \
        }                                                                    \
    }
    STAGE_XT(0);
    __syncthreads();

    #pragma unroll
    for (int ks = 0; ks < 4; ++ks) {
        if (ks == 2) {
            __syncthreads();
            STAGE_XT(1);
            __syncthreads();
        }
        const int k0 = ks * 32 + lr * 8;
        const int kl = (ks & 1) * 32 + lr * 8;
        s16x8 gh4[4], gl4[4], xf[2];
        #pragma unroll
        for (int f = 0; f < 4; ++f) {
            const int rowi = wr * 64 + f * 16 + lc;
            const float4 g0 = *(const float4*)&Gw[rowi * GWF + k0];
            const float4 g1 = *(const float4*)&Gw[rowi * GWF + k0 + 4];
            split8(g0, g1, gh4[f], gl4[f]);
        }
        #pragma unroll
        for (int f = 0; f < 2; ++f) {
            const int rowp = wc * 32 + f * 16 + lc;
            xf[f] = *(const s16x8*)&XTh[rowp * XTS + kl];
        }
        #pragma unroll
        for (int fm = 0; fm < 4; ++fm)
            #pragma unroll
            for (int fn = 0; fn < 2; ++fn) {
                accY[fm][fn] = __builtin_amdgcn_mfma_f32_16x16x32_bf16(
                    gh4[fm], xf[fn], accY[fm][fn], 0, 0, 0);
                accY[fm][fn] = __builtin_amdgcn_mfma_f32_16x16x32_bf16(
                    gl4[fm], xf[fn], accY[fm][fn], 0, 0, 0);
            }
    }
#undef STAGE_XT

    #pragma unroll
    for (int fm = 0; fm < 4; ++fm)
        #pragma unroll
        for (int fn = 0; fn < 2; ++fn) {
            const int p = wc * 32 + fn * 16 + lc;
            #pragma unroll
            for (int jj = 0; jj < 4; ++jj) {
                const int i = wr * 64 + fm * 16 + lr * 4 + jj;
                yb[((size_t)b * LSEQ + t0 + i) * DIN + h * 64 + p] = accY[fm][fn][jj];
            }
        }
}

// ---------------------------------------------------------------------------
// merged gate+RMS-norm (blocks 0..2047) and out_proj_w conversion (rest).
// ---------------------------------------------------------------------------
__global__ __launch_bounds__(256) void gate_convwo(const float* __restrict__ yb,
        const float* __restrict__ zx, const float* __restrict__ norm_w,
        u16* __restrict__ gnb, const float* __restrict__ wo_src,
        u16* __restrict__ wo_hi) {
    if (blockIdx.x < ROWS) {
        const int bl = blockIdx.x;
        const int tid = threadIdx.x;
        const float* yrow = yb + (size_t)bl * DIN;
        const float* zrow = zx + (size_t)bl * DTOT + OFF_Z;
        float g[8];
        float ss = 0.f;
        #pragma unroll
        for (int i = 0; i < 8; ++i) {
            const int c = tid + i * 256;
            const float yv = yrow[c];
            const float zv = zrow[c];
            const float sg = 1.f / (1.f + expf(-zv));
            const float gv = yv * zv * sg;
            g[i] = gv;
            ss += gv * gv;
        }
        #pragma unroll
        for (int k = 1; k < 64; k <<= 1) ss += __shfl_xor(ss, k);
        __shared__ float wsum[4];
        if ((tid & 63) == 0) wsum[tid >> 6] = ss;
        __syncthreads();
        ss = wsum[0] + wsum[1] + wsum[2] + wsum[3];
        const float sc = rsqrtf(ss * (1.f / 2048.f) + 1e-5f);
        #pragma unroll
        for (int i = 0; i < 8; ++i) {
            const int c = tid + i * 256;
            gnb[(size_t)bl * DIN + c] = (u16)f2bf(g[i] * sc * norm_w[c]);
        }
    } else {
        const size_t i4 = ((size_t)(blockIdx.x - ROWS) * 256 + threadIdx.x) * 4;
        const float4 v = *(const float4*)(wo_src + i4);
        uint2 hw;
        hw.x = pk(v.x, v.y); hw.y = pk(v.z, v.w);
        *(uint2*)(wo_hi + i4) = hw;
    }
}

// ---------------------------------------------------------------------------
extern "C" void kernel_launch(void* const* d_in, const int* in_sizes, int n_in,
                              void* d_out, int out_size, void* d_ws, size_t ws_size,
                              hipStream_t stream) {
    const float* u          = (const float*)d_in[0];
    const float* in_proj_w  = (const float*)d_in[1];
    const float* dt_bias    = (const float*)d_in[2];
    const float* A_log      = (const float*)d_in[3];
    const float* Dp         = (const float*)d_in[4];
    const float* B_norm_w   = (const float*)d_in[5];
    const float* C_norm_w   = (const float*)d_in[6];
    const float* B_bias     = (const float*)d_in[7];
    const float* C_bias     = (const float*)d_in[8];
    const float* norm_w     = (const float*)d_in[9];
    const float* out_proj_w = (const float*)d_in[10];
    float* out = (float*)d_out;

    float* p = (float*)d_ws;
    float* zx    = p; p += (size_t)ROWS * DTOT;
    float* th_cs = p; p += (size_t)ROWS * 1024;   // dead after rot -> hseg
    float* Brot  = p; p += (size_t)ROWS * 2048;   // doubles as bf16 scratch
    float* Crot  = p; p += (size_t)ROWS * 2048;
    float* Bg    = p; p += (size_t)ROWS * 64;     // dead after rot -> aprod/bscale/Lbuf
    float* Cg    = p; p += (size_t)ROWS * 64;     // dead after rot -> wbuf
    float4* abg4 = (float4*)p; p += (size_t)ROWS * NH * 4;
    float* yb    = p; p += (size_t)ROWS * 2048;
    float* hseg   = th_cs;
    float* aprod  = Bg;
    float* bscale = Bg + 512;
    float* Lbuf   = Bg + 2048;
    float* wbuf   = Cg;

    u16* u_bf = (u16*)Brot;
    u16* u_lo = u_bf + (size_t)ROWS * DMODEL;
    u16* w_bf = u_lo + (size_t)ROWS * DMODEL;
    u16* w_lo = w_bf + (size_t)DTOT * DMODEL;
    u16* gn_bf = (u16*)Brot;
    u16* wo_bf = gn_bf + (size_t)ROWS * DIN;

    conv_uw<<<CONV_U_BLOCKS + CONV_W_BLOCKS, 256, 0, stream>>>(
        u, in_proj_w, u_bf, u_lo, w_bf, w_lo);
    mfma_inproj<<<ZX_BLOCKS + R3_BLOCKS, 256, 0, stream>>>(
        u_bf, u_lo, w_bf, w_lo, zx);
    prep_cumsum<<<512 + BB * NH, 256, 0, stream>>>(zx, dt_bias, A_log, B_norm_w,
                                                   C_norm_w, Bg, Cg, abg4, th_cs);
    rot_kernel<<<(ROWS * 1024) / 256, 256, 0, stream>>>(th_cs, Bg, Cg, B_bias, C_bias,
                                                        Brot, Crot);
    wcalc_kernel<<<BB * NH, 64, 0, stream>>>(abg4, wbuf, aprod, bscale, Lbuf);
    hseg_gemm<<<BB * NH * NSEG, 256, 0, stream>>>(zx, Brot, wbuf, hseg);
    scan_fix<<<BB * NH * 4, 256, 0, stream>>>(hseg, aprod, bscale, zx, Brot, abg4);
    ssd_y<<<BB * NH * NSEG, 256, 0, stream>>>(zx, Brot, Crot, abg4, hseg, Lbuf, Dp, yb);
    gate_convwo<<<ROWS + (DMODEL * DIN / 4) / 256, 256, 0, stream>>>(
        yb, zx, norm_w, gn_bf, out_proj_w, wo_bf);
    mfma_gemm_out<<<dim3(DMODEL / 64, ROWS / 128), 256, 0, stream>>>(
        gn_bf, wo_bf, out, DIN, DMODEL);
}

// Round 23
// 175.251 us; speedup vs baseline: 2.0200x; 1.0040x over previous
//
#include <hip/hip_runtime.h>
#include <hip/hip_bf16.h>

// Problem constants
#define DMODEL 1024
#define DIN    2048
#define NH     32
#define HD     64
#define DS     64
#define LSEQ   1024
#define BB     2
#define DTOT   5312           // 2*DIN + 2*64 + 32 + 1024 + 32
#define ROWS   (BB*LSEQ)      // 2048
// column offsets inside zxbcdt
#define OFF_Z   0
#define OFF_X   2048
#define OFF_BR  4096
#define OFF_CR  4160
#define OFF_DT  4224
#define OFF_TH  4256
#define OFF_LAM 5280
#define NZX     4096          // z+x columns: single-pass bf16 MFMA
#define NREM    (DTOT - NZX)  // 1216 cols: 3-pass split-bf16 MFMA
// segmented scan
#define NSEG 8
#define SEG  (LSEQ / NSEG)    // 128

typedef short  s16x8 __attribute__((ext_vector_type(8)));
typedef float  f32x4 __attribute__((ext_vector_type(4)));
typedef unsigned short u16;

__device__ __forceinline__ unsigned int f2bf(float f) {   // RNE f32->bf16 (finite inputs)
    unsigned int u = __float_as_uint(f);
    u += 0x7fffu + ((u >> 16) & 1u);
    return u >> 16;
}
__device__ __forceinline__ unsigned int pk(float x, float y) {
    return f2bf(x) | (f2bf(y) << 16);
}
__device__ __forceinline__ void split1(float v, u16& hi, u16& lo) {
    const unsigned int h = f2bf(v);
    hi = (u16)h;
    lo = (u16)f2bf(v - __uint_as_float(h << 16));
}
__device__ __forceinline__ void split8(const float4 a, const float4 b,
                                       s16x8& hi, s16x8& lo) {
    u16 h_, l_;
    split1(a.x, h_, l_); hi[0] = (short)h_; lo[0] = (short)l_;
    split1(a.y, h_, l_); hi[1] = (short)h_; lo[1] = (short)l_;
    split1(a.z, h_, l_); hi[2] = (short)h_; lo[2] = (short)l_;
    split1(a.w, h_, l_); hi[3] = (short)h_; lo[3] = (short)l_;
    split1(b.x, h_, l_); hi[4] = (short)h_; lo[4] = (short)l_;
    split1(b.y, h_, l_); hi[5] = (short)h_; lo[5] = (short)l_;
    split1(b.z, h_, l_); hi[6] = (short)h_; lo[6] = (short)l_;
    split1(b.w, h_, l_); hi[7] = (short)h_; lo[7] = (short)l_;
}
__device__ __forceinline__ void cvt8(const float4 a, const float4 b, s16x8& hi) {
    hi[0] = (short)f2bf(a.x); hi[1] = (short)f2bf(a.y);
    hi[2] = (short)f2bf(a.z); hi[3] = (short)f2bf(a.w);
    hi[4] = (short)f2bf(b.x); hi[5] = (short)f2bf(b.y);
    hi[6] = (short)f2bf(b.z); hi[7] = (short)f2bf(b.w);
}

// HBM -> LDS direct 16B copy. Dest = wave-uniform base + lane*16 (m104).
typedef const __attribute__((address_space(1))) unsigned int glb_u32;
typedef __attribute__((address_space(3))) unsigned int lds_u32;
__device__ __forceinline__ void gload16(const void* g, void* l) {
    __builtin_amdgcn_global_load_lds((glb_u32*)g, (lds_u32*)l, 16, 0, 0);
}

// XOR swizzles (involutions; source chunk + LDS read index; rule #21).
#define SWZ(row)  (((row) >> 1) & 3)   // 4 chunks/row  (BK=32 tiles)
#define SWZ8(row) (((row) >> 1) & 7)   // 8 chunks/row  (BK=64 tiles)

// ---------------------------------------------------------------------------
// merged conversion kernel: u (blocks 0..2047) and in_proj_w (rest).
// ---------------------------------------------------------------------------
#define CONV_U_BLOCKS (ROWS * DMODEL / 4 / 256)           // 2048
#define CONV_W_BLOCKS ((DTOT * DMODEL / 4) / 256)         // 5312
__global__ __launch_bounds__(256) void conv_uw(const float* __restrict__ usrc,
        const float* __restrict__ wsrc, u16* __restrict__ u_hi,
        u16* __restrict__ u_lo, u16* __restrict__ w_hi, u16* __restrict__ w_lo) {
    const int bid = blockIdx.x;
    if (bid < CONV_U_BLOCKS) {
        const size_t i4 = ((size_t)bid * 256 + threadIdx.x) * 4;
        const float4 v = *(const float4*)(usrc + i4);
        const unsigned int h0 = f2bf(v.x), h1 = f2bf(v.y), h2 = f2bf(v.z), h3 = f2bf(v.w);
        uint2 hw, lw;
        hw.x = h0 | (h1 << 16); hw.y = h2 | (h3 << 16);
        lw.x = pk(v.x - __uint_as_float(h0 << 16), v.y - __uint_as_float(h1 << 16));
        lw.y = pk(v.z - __uint_as_float(h2 << 16), v.w - __uint_as_float(h3 << 16));
        *(uint2*)(u_hi + i4) = hw;
        *(uint2*)(u_lo + i4) = lw;
    } else {
        const size_t i4 = ((size_t)(bid - CONV_U_BLOCKS) * 256 + threadIdx.x) * 4;
        const float4 v = *(const float4*)(wsrc + i4);
        const unsigned int h0 = f2bf(v.x), h1 = f2bf(v.y), h2 = f2bf(v.z), h3 = f2bf(v.w);
        uint2 hw, lw;
        hw.x = h0 | (h1 << 16); hw.y = h2 | (h3 << 16);
        lw.x = pk(v.x - __uint_as_float(h0 << 16), v.y - __uint_as_float(h1 << 16));
        lw.y = pk(v.z - __uint_as_float(h2 << 16), v.w - __uint_as_float(h3 << 16));
        *(uint2*)(w_hi + i4) = hw;
        if ((i4 >> 10) >= NZX)
            *(uint2*)(w_lo + (i4 - (size_t)NZX * DMODEL)) = lw;
    }
}

// ---------------------------------------------------------------------------
// merged in_proj GEMM: blocks 0..511 = z/x tiles (BK=64), 512..815 = rem3.
// z/x tiles use a T1 XCD-aware 8x8-region remap: XCD k (= bid%8 under
// round-robin dispatch) owns an 8x8 tile region -> per-XCD working set
// A 2MB + B 2MB = 4MB = L2 size (vs 5MB thrashing with the linear map).
// Bijective: 2x4 regions x 64 blocks cover the 16x32 tile grid.
// ---------------------------------------------------------------------------
#define ZX_BLOCKS 512
#define R3_BLOCKS ((NREM / 64) * (ROWS / 128))   // 19*16 = 304
__global__ __launch_bounds__(256) void mfma_inproj(const u16* __restrict__ u_bf,
        const u16* __restrict__ u_lo, const u16* __restrict__ w_bf,
        const u16* __restrict__ w_lo, float* __restrict__ zx) {
    __shared__ u16 smem[32768];    // 64 KB union
    const int tid = threadIdx.x;
    const int lane = tid & 63, wave = tid >> 6;
    const int wr = wave >> 1, wc = wave & 1;
    const int lr = lane >> 4, lc = lane & 15;

    if (blockIdx.x < ZX_BLOCKS) {
        // ---------------- z/x branch (BK=64, XCD-region remap) ----------------
        const int bid = blockIdx.x;
        const int kx = bid & 7, lx = bid >> 3;
        const int mt = (kx >> 2) * 8 + (lx >> 3);   // 0..15
        const int nt = (kx & 3) * 8 + (lx & 7);     // 0..31
        const int m0 = mt * 128, n0 = nt * 128;
        const int sr = tid >> 3;
        const int sc = (((tid & 7) ^ ((tid >> 4) & 7)) * 8);
        f32x4 acc[4][4] = {};
        const u16* pA = u_bf + (size_t)(m0 + sr) * DMODEL + sc;
        const u16* pB = w_bf + (size_t)(n0 + sr) * DMODEL + sc;
        u16* Al = smem;              // buf stride 8192 u16
        u16* Bl = smem + 16384;

#define STAGE_ZX(buf, k0) {                                                       \
        gload16(pA + (k0),                       Al + (buf)*8192 + tid*8);        \
        gload16(pA + (k0) + (size_t)32 * DMODEL, Al + (buf)*8192 + tid*8 + 2048); \
        gload16(pA + (k0) + (size_t)64 * DMODEL, Al + (buf)*8192 + tid*8 + 4096); \
        gload16(pA + (k0) + (size_t)96 * DMODEL, Al + (buf)*8192 + tid*8 + 6144); \
        gload16(pB + (k0),                       Bl + (buf)*8192 + tid*8);        \
        gload16(pB + (k0) + (size_t)32 * DMODEL, Bl + (buf)*8192 + tid*8 + 2048); \
        gload16(pB + (k0) + (size_t)64 * DMODEL, Bl + (buf)*8192 + tid*8 + 4096); \
        gload16(pB + (k0) + (size_t)96 * DMODEL, Bl + (buf)*8192 + tid*8 + 6144); }

        STAGE_ZX(0, 0);
        __syncthreads();
        int cur = 0;
        for (int k0 = 0; k0 < DMODEL; k0 += 64) {
            if (k0 + 64 < DMODEL) STAGE_ZX(cur ^ 1, k0 + 64);
            #pragma unroll
            for (int kk = 0; kk < 2; ++kk) {
                s16x8 af[4], bf[4];
                #pragma unroll
                for (int f = 0; f < 4; ++f) {
                    const int ra = wr * 64 + f * 16 + lc;
                    af[f] = *(const s16x8*)&Al[cur * 8192 + ra * 64 + (((kk * 4 + lr) ^ SWZ8(ra)) * 8)];
                    const int rb = wc * 64 + f * 16 + lc;
                    bf[f] = *(const s16x8*)&Bl[cur * 8192 + rb * 64 + (((kk * 4 + lr) ^ SWZ8(rb)) * 8)];
                }
                #pragma unroll
                for (int fm = 0; fm < 4; ++fm)
                    #pragma unroll
                    for (int fn = 0; fn < 4; ++fn)
                        acc[fm][fn] = __builtin_amdgcn_mfma_f32_16x16x32_bf16(
                            af[fm], bf[fn], acc[fm][fn], 0, 0, 0);
            }
            __syncthreads();
            cur ^= 1;
        }
#undef STAGE_ZX

        #pragma unroll
        for (int fm = 0; fm < 4; ++fm)
            #pragma unroll
            for (int fn = 0; fn < 4; ++fn) {
                const size_t col = n0 + wc * 64 + fn * 16 + lc;
                #pragma unroll
                for (int j = 0; j < 4; ++j) {
                    const size_t row = m0 + wr * 64 + fm * 16 + lr * 4 + j;
                    zx[row * DTOT + col] = acc[fm][fn][j];
                }
            }
    } else {
        // ---------------- rem3 branch (BK=32, 3-pass split) ----------------
        const int rid = blockIdx.x - ZX_BLOCKS;
        const int m0 = (rid / (NREM / 64)) * 128, n0 = (rid % (NREM / 64)) * 64;
        const int sr = tid >> 2;
        const int sc = (((tid & 3) ^ SWZ(tid >> 2)) * 8);
        f32x4 acc[4][2] = {};
        const u16* pAh = u_bf + (size_t)(m0 + sr) * DMODEL + sc;
        const u16* pAl = u_lo + (size_t)(m0 + sr) * DMODEL + sc;
        const u16* pBh = w_bf + (size_t)(NZX + n0 + sr) * DMODEL + sc;
        const u16* pBl = w_lo + (size_t)(n0 + sr) * DMODEL + sc;
        u16* Ah  = smem;             // buf stride 4096 u16
        u16* Alo = smem + 8192;
        u16* Bh  = smem + 16384;     // buf stride 2048 u16
        u16* Blo = smem + 20480;

#define STAGE_R3(buf, k0) {                                                          \
        gload16(pAh + (k0),                       Ah  + (buf)*4096 + tid*8);         \
        gload16(pAh + (k0) + (size_t)64 * DMODEL, Ah  + (buf)*4096 + tid*8 + 2048);  \
        gload16(pAl + (k0),                       Alo + (buf)*4096 + tid*8);         \
        gload16(pAl + (k0) + (size_t)64 * DMODEL, Alo + (buf)*4096 + tid*8 + 2048);  \
        gload16(pBh + (k0),                       Bh  + (buf)*2048 + tid*8);         \
        gload16(pBl + (k0),                       Blo + (buf)*2048 + tid*8); }

        STAGE_R3(0, 0);
        __syncthreads();
        int cur = 0;
        for (int k0 = 0; k0 < DMODEL; k0 += 32) {
            if (k0 + 32 < DMODEL) STAGE_R3(cur ^ 1, k0 + 32);
            s16x8 ahf[4], alf[4], bhf[2], blf[2];
            #pragma unroll
            for (int f = 0; f < 4; ++f) {
                const int ra = wr * 64 + f * 16 + lc;
                const int oa = ra * 32 + ((lr ^ SWZ(ra)) * 8);
                ahf[f] = *(const s16x8*)&Ah[cur * 4096 + oa];
                alf[f] = *(const s16x8*)&Alo[cur * 4096 + oa];
            }
            #pragma unroll
            for (int f = 0; f < 2; ++f) {
                const int rb = wc * 32 + f * 16 + lc;
                const int ob = rb * 32 + ((lr ^ SWZ(rb)) * 8);
                bhf[f] = *(const s16x8*)&Bh[cur * 2048 + ob];
                blf[f] = *(const s16x8*)&Blo[cur * 2048 + ob];
            }
            #pragma unroll
            for (int fm = 0; fm < 4; ++fm)
                #pragma unroll
                for (int fn = 0; fn < 2; ++fn) {
                    acc[fm][fn] = __builtin_amdgcn_mfma_f32_16x16x32_bf16(
                        ahf[fm], bhf[fn], acc[fm][fn], 0, 0, 0);
                    acc[fm][fn] = __builtin_amdgcn_mfma_f32_16x16x32_bf16(
                        ahf[fm], blf[fn], acc[fm][fn], 0, 0, 0);
                    acc[fm][fn] = __builtin_amdgcn_mfma_f32_16x16x32_bf16(
                        alf[fm], bhf[fn], acc[fm][fn], 0, 0, 0);
                }
            __syncthreads();
            cur ^= 1;
        }
#undef STAGE_R3

        #pragma unroll
        for (int fm = 0; fm < 4; ++fm)
            #pragma unroll
            for (int fn = 0; fn < 2; ++fn) {
                const size_t col = NZX + n0 + wc * 32 + fn * 16 + lc;
                #pragma unroll
                for (int j = 0; j < 4; ++j) {
                    const size_t row = m0 + wr * 64 + fm * 16 + lr * 4 + j;
                    zx[row * DTOT + col] = acc[fm][fn][j];
                }
            }
    }
}

// ---------------------------------------------------------------------------
// bf16 MFMA GEMM, 128x64 tile, BK=64: out = gn_bf @ wo_bf^T (LDS 48KB)
// ---------------------------------------------------------------------------
__global__ __launch_bounds__(256) void mfma_gemm_out(const u16* __restrict__ A,
                                                     const u16* __restrict__ B,
                                                     float* __restrict__ C,
                                                     int K, int ldc) {
    __shared__ u16 Als[2][128 * 64];
    __shared__ u16 Bls[2][64 * 64];
    const int tid = threadIdx.x;
    const int m0 = blockIdx.y * 128, n0 = blockIdx.x * 64;
    const int lane = tid & 63, wave = tid >> 6;
    const int wr = wave >> 1, wc = wave & 1;
    const int lr = lane >> 4, lc = lane & 15;
    const int sr = tid >> 3;
    const int sc = (((tid & 7) ^ ((tid >> 4) & 7)) * 8);

    f32x4 acc[4][2] = {};

    const u16* pA = A + (size_t)(m0 + sr) * K + sc;
    const u16* pB = B + (size_t)(n0 + sr) * K + sc;

#define STAGE_OUT(buf, k0) {                                                  \
        gload16(pA + (k0),                   &Als[buf][tid * 8]);             \
        gload16(pA + (k0) + (size_t)32 * K,  &Als[buf][tid * 8 + 2048]);      \
        gload16(pA + (k0) + (size_t)64 * K,  &Als[buf][tid * 8 + 4096]);      \
        gload16(pA + (k0) + (size_t)96 * K,  &Als[buf][tid * 8 + 6144]);      \
        gload16(pB + (k0),                   &Bls[buf][tid * 8]);             \
        gload16(pB + (k0) + (size_t)32 * K,  &Bls[buf][tid * 8 + 2048]); }

    STAGE_OUT(0, 0);
    __syncthreads();
    int cur = 0;
    for (int k0 = 0; k0 < K; k0 += 64) {
        if (k0 + 64 < K) STAGE_OUT(cur ^ 1, k0 + 64);
        #pragma unroll
        for (int kk = 0; kk < 2; ++kk) {
            s16x8 af[4], bf[2];
            #pragma unroll
            for (int f = 0; f < 4; ++f) {
                const int ra = wr * 64 + f * 16 + lc;
                af[f] = *(const s16x8*)&Als[cur][ra * 64 + (((kk * 4 + lr) ^ SWZ8(ra)) * 8)];
            }
            #pragma unroll
            for (int f = 0; f < 2; ++f) {
                const int rb = wc * 32 + f * 16 + lc;
                bf[f] = *(const s16x8*)&Bls[cur][rb * 64 + (((kk * 4 + lr) ^ SWZ8(rb)) * 8)];
            }
            #pragma unroll
            for (int fm = 0; fm < 4; ++fm)
                #pragma unroll
                for (int fn = 0; fn < 2; ++fn)
                    acc[fm][fn] = __builtin_amdgcn_mfma_f32_16x16x32_bf16(
                        af[fm], bf[fn], acc[fm][fn], 0, 0, 0);
        }
        __syncthreads();
        cur ^= 1;
    }
#undef STAGE_OUT

    #pragma unroll
    for (int fm = 0; fm < 4; ++fm)
        #pragma unroll
        for (int fn = 0; fn < 2; ++fn) {
            const size_t col = n0 + wc * 32 + fn * 16 + lc;
            #pragma unroll
            for (int j = 0; j < 4; ++j) {
                const size_t row = m0 + wr * 64 + fm * 16 + lr * 4 + j;
                C[row * (size_t)ldc + col] = acc[fm][fn][j];
            }
        }
}

// ---------------------------------------------------------------------------
// merged prep + cumsum (both only READ zx; outputs disjoint -> race-free).
// ---------------------------------------------------------------------------
__global__ __launch_bounds__(256) void prep_cumsum(const float* __restrict__ zx,
        const float* __restrict__ dt_bias, const float* __restrict__ A_log,
        const float* __restrict__ B_norm_w, const float* __restrict__ C_norm_w,
        float* __restrict__ Bg, float* __restrict__ Cg,
        float4* __restrict__ abg4, float* __restrict__ th_cs) {
    __shared__ float sums[8][33];
    const int bid = blockIdx.x;
    const int tid = threadIdx.x;
    if (bid < 512) {
        const int bl = bid * 4 + (tid >> 6);
        const int t  = tid & 63;
        const int b = bl >> 10, l = bl & (LSEQ - 1);
        const float* row = zx + (size_t)bl * DTOT;
        const float br = row[OFF_BR + t];
        const float cr = row[OFF_CR + t];
        float ssb = br * br, ssc = cr * cr;
        #pragma unroll
        for (int k = 1; k < 64; k <<= 1) { ssb += __shfl_xor(ssb, k); ssc += __shfl_xor(ssc, k); }
        const float scB = rsqrtf(ssb * (1.f / 64.f) + 1e-5f);
        const float scC = rsqrtf(ssc * (1.f / 64.f) + 1e-5f);
        Bg[(size_t)bl * 64 + t] = br * scB * B_norm_w[t];
        Cg[(size_t)bl * 64 + t] = cr * scC * C_norm_w[t];
        if (t < NH) {
            const float dtr = row[OFF_DT + t] + dt_bias[t];
            const float dt  = (dtr > 20.f) ? dtr : log1pf(expf(dtr));
            const float lamr = row[OFF_LAM + t];
            const float lam  = 1.f / (1.f + expf(-lamr));
            const float Ah   = -expf(A_log[t]);
            const float al   = expf(dt * Ah);
            const float bp   = (1.f - lam) * dt;        // beta' = b/a
            const size_t o = ((size_t)b * NH + t) * LSEQ + l;
            abg4[o] = make_float4(al, bp * al, lam * dt, bp);
        }
    } else {
        const int bh = bid - 512;
        const int b = bh >> 5, h = bh & 31;
        const int d = tid & 31, seg = tid >> 5;
        const float* base = zx + (size_t)b * LSEQ * DTOT + OFF_TH + h * 32 + d;
        float* out = th_cs + (size_t)b * LSEQ * 1024 + h * 32 + d;
        const int l0 = seg * 128;
        float s = 0.f;
        #pragma unroll 4
        for (int i = 0; i < 128; ++i) s += base[(size_t)(l0 + i) * DTOT];
        sums[seg][d] = s;
        __syncthreads();
        float acc = 0.f;
        for (int s2 = 0; s2 < seg; ++s2) acc += sums[s2][d];
        #pragma unroll 4
        for (int i = 0; i < 128; ++i) {
            acc += base[(size_t)(l0 + i) * DTOT];
            out[(size_t)(l0 + i) * 1024] = acc;
        }
    }
}

// ---------------------------------------------------------------------------
// rot: Bh/Ch = rot(broadcast(Bg/Cg)+bias). Brot/Crot layout (B,NH,L,DS).
// ---------------------------------------------------------------------------
__global__ __launch_bounds__(256) void rot_kernel(const float* __restrict__ th_cs,
        const float* __restrict__ Bg, const float* __restrict__ Cg,
        const float* __restrict__ B_bias, const float* __restrict__ C_bias,
        float* __restrict__ Brot, float* __restrict__ Crot) {
    const size_t idx = (size_t)blockIdx.x * 256 + threadIdx.x;
    const int j = (int)(idx & 31);
    const int h = (int)((idx >> 5) & 31);
    const size_t bl = idx >> 10;
    const int l = (int)(bl & (LSEQ - 1));
    const int b = (int)(bl >> 10);
    const float th = th_cs[idx];
    float s, c;
    sincosf(th, &s, &c);
    float v1 = Bg[bl * 64 + j]      + B_bias[h * 64 + j];
    float v2 = Bg[bl * 64 + 32 + j] + B_bias[h * 64 + 32 + j];
    const size_t ob = ((size_t)(b * NH + h) * LSEQ + l) * DS + j;
    Brot[ob]      = v1 * c - v2 * s;
    Brot[ob + 32] = v1 * s + v2 * c;
    v1 = Cg[bl * 64 + j]      + C_bias[h * 64 + j];
    v2 = Cg[bl * 64 + 32 + j] + C_bias[h * 64 + 32 + j];
    Crot[ob]      = v1 * c - v2 * s;
    Crot[ob + 32] = v1 * s + v2 * c;
}

// ---------------------------------------------------------------------------
// wcalc: per (b,h,seg): within-seg log-cumsum of alpha; emits
//   wbuf[t], Lbuf[t], aprod[s], bscale[s]  (round 13/15 derivation)
// ---------------------------------------------------------------------------
__global__ __launch_bounds__(64) void wcalc_kernel(const float4* __restrict__ abg4,
        float* __restrict__ wbuf, float* __restrict__ aprod,
        float* __restrict__ bscale, float* __restrict__ Lbuf) {
    const int bh = blockIdx.x;
    const int lane = threadIdx.x;
    const int seg = lane >> 3, sub = lane & 7;
    const int t0 = seg * SEG;
    const int sbase = t0 + sub * 16;
    const float4* ab = abg4 + (size_t)bh * LSEQ;

    float part = 0.f;
    #pragma unroll
    for (int i = 0; i < 16; ++i) part += logf(ab[sbase + i].x);
    float incl = part;
    #pragma unroll
    for (int d = 1; d < 8; d <<= 1) {
        const float v = __shfl_up(incl, d, 8);
        if (sub >= d) incl += v;
    }
    const float LE = __shfl(incl, 7, 8);
    float Lrun = incl - part;                // exclusive prefix

    for (int i = 0; i < 16; ++i) {
        const int s = sbase + i;
        const float4 A = ab[s];
        Lrun += logf(A.x);
        Lbuf[(size_t)bh * LSEQ + s] = Lrun;
        float w;
        if ((s & (SEG - 1)) == (SEG - 1)) w = A.z;
        else w = __expf(LE - Lrun) * (A.z + ab[s + 1].w);
        wbuf[(size_t)bh * LSEQ + s] = w;
    }
    if (sub == 0) {
        aprod[bh * NSEG + seg] = __expf(LE);
        bscale[bh * NSEG + seg] = (seg > 0) ? __expf(LE) * ab[t0].w : 0.f;
    }
}

// ---------------------------------------------------------------------------
// hseg_gemm: h_local_end[p,n] = sum_s wbuf_s * x_s[p] * B_s[n] (split-bf16 3-pass)
// ---------------------------------------------------------------------------
#define WK 136
__global__ __launch_bounds__(256) void hseg_gemm(const float* __restrict__ zx,
        const float* __restrict__ Brot, const float* __restrict__ wbuf,
        float* __restrict__ hseg) {
    __shared__ u16 XH[64][WK], XL[64][WK], BHs[64][WK], BLs[64][WK];
    const int blk = blockIdx.x;
    const int seg = blk & (NSEG - 1), bh = blk >> 3;
    const int b = bh >> 5, h = bh & 31;
    const int tid = threadIdx.x;

    {
        const int sIdx = tid >> 1, half = tid & 1;
        const int t = seg * SEG + sIdx;
        const float wv = wbuf[(size_t)bh * LSEQ + t];
        const float* xsrc = zx + ((size_t)b * LSEQ + t) * DTOT + OFF_X + h * 64 + half * 32;
        const float* bsrc = Brot + ((size_t)bh * LSEQ + t) * DS + half * 32;
        #pragma unroll
        for (int i = 0; i < 32; i += 4) {
            const float4 xv = *(const float4*)(xsrc + i);
            const float4 bv = *(const float4*)(bsrc + i);
            const int p0 = half * 32 + i;
            u16 hi, lo;
            split1(xv.x * wv, hi, lo); XH[p0 + 0][sIdx] = hi; XL[p0 + 0][sIdx] = lo;
            split1(xv.y * wv, hi, lo); XH[p0 + 1][sIdx] = hi; XL[p0 + 1][sIdx] = lo;
            split1(xv.z * wv, hi, lo); XH[p0 + 2][sIdx] = hi; XL[p0 + 2][sIdx] = lo;
            split1(xv.w * wv, hi, lo); XH[p0 + 3][sIdx] = hi; XL[p0 + 3][sIdx] = lo;
            split1(bv.x, hi, lo); BHs[p0 + 0][sIdx] = hi; BLs[p0 + 0][sIdx] = lo;
            split1(bv.y, hi, lo); BHs[p0 + 1][sIdx] = hi; BLs[p0 + 1][sIdx] = lo;
            split1(bv.z, hi, lo); BHs[p0 + 2][sIdx] = hi; BLs[p0 + 2][sIdx] = lo;
            split1(bv.w, hi, lo); BHs[p0 + 3][sIdx] = hi; BLs[p0 + 3][sIdx] = lo;
        }
    }
    __syncthreads();

    const int lane = tid & 63, wave = tid >> 6;
    const int wR = wave >> 1, wC = wave & 1;
    const int lr = lane >> 4, lc = lane & 15;

    f32x4 acc[2][2] = {};
    #pragma unroll
    for (int ks = 0; ks < 4; ++ks) {
        const int k0 = ks * 32;
        s16x8 xh[2], xl[2], bhf[2], blf[2];
        #pragma unroll
        for (int f = 0; f < 2; ++f) {
            const int pr = wR * 32 + f * 16 + lc;
            xh[f] = *(const s16x8*)&XH[pr][k0 + lr * 8];
            xl[f] = *(const s16x8*)&XL[pr][k0 + lr * 8];
            const int nr = wC * 32 + f * 16 + lc;
            bhf[f] = *(const s16x8*)&BHs[nr][k0 + lr * 8];
            blf[f] = *(const s16x8*)&BLs[nr][k0 + lr * 8];
        }
        #pragma unroll
        for (int fm = 0; fm < 2; ++fm)
            #pragma unroll
            for (int fn = 0; fn < 2; ++fn) {
                acc[fm][fn] = __builtin_amdgcn_mfma_f32_16x16x32_bf16(
                    xh[fm], bhf[fn], acc[fm][fn], 0, 0, 0);
                acc[fm][fn] = __builtin_amdgcn_mfma_f32_16x16x32_bf16(
                    xh[fm], blf[fn], acc[fm][fn], 0, 0, 0);
                acc[fm][fn] = __builtin_amdgcn_mfma_f32_16x16x32_bf16(
                    xl[fm], bhf[fn], acc[fm][fn], 0, 0, 0);
            }
    }

    float* hp = hseg + ((size_t)(bh * NSEG + seg) * HD) * DS;
    #pragma unroll
    for (int fm = 0; fm < 2; ++fm)
        #pragma unroll
        for (int fn = 0; fn < 2; ++fn) {
            const int n = wC * 32 + fn * 16 + lc;
            #pragma unroll
            for (int j = 0; j < 4; ++j) {
                const int p = wR * 32 + fm * 16 + lr * 4 + j;
                hp[p * DS + n] = acc[fm][fn][j];
            }
        }
}

// ---------------------------------------------------------------------------
// scan_fix: sequential over segments -> hseg becomes hstar per segment.
// ---------------------------------------------------------------------------
__global__ __launch_bounds__(256) void scan_fix(float* __restrict__ hseg,
        const float* __restrict__ aprod, const float* __restrict__ bscale,
        const float* __restrict__ zx, const float* __restrict__ Brot,
        const float4* __restrict__ abg4) {
    const int blk = blockIdx.x;          // (b,h,ptile): 256
    const int ptile = blk & 3, h = (blk >> 2) & 31, b = blk >> 7;
    const int tid = threadIdx.x;
    const int pl = tid >> 4, ng = tid & 15;
    const int p = ptile * 16 + pl;
    const int n0 = ng * 4;
    const size_t bh = (size_t)b * NH + h;

    float4 cur = make_float4(0.f, 0.f, 0.f, 0.f);
    #pragma unroll
    for (int s = 0; s < NSEG; ++s) {
        float* hp = hseg + (((bh * NSEG + s) * HD + p) * DS + n0);
        float4 tmp = *(const float4*)hp;     // local h_end (no boundary)
        float4 hst = cur;                    // hstar = h_start (+ r1 below)
        if (s > 0) {
            const float bs = bscale[bh * NSEG + s];          // aprod*beta'
            const float bp0 = abg4[bh * LSEQ + s * SEG].w;   // beta'_{t0}
            const int tm1 = s * SEG - 1;
            const float4 Bm = *(const float4*)(Brot + ((size_t)bh * LSEQ + tm1) * DS + n0);
            const float xm = zx[((size_t)b * LSEQ + tm1) * DTOT + OFF_X + h * HD + p];
            const float fb = bs * xm;
            const float f1 = bp0 * xm;
            tmp.x = fmaf(fb, Bm.x, tmp.x);
            tmp.y = fmaf(fb, Bm.y, tmp.y);
            tmp.z = fmaf(fb, Bm.z, tmp.z);
            tmp.w = fmaf(fb, Bm.w, tmp.w);
            hst.x = fmaf(f1, Bm.x, hst.x);
            hst.y = fmaf(f1, Bm.y, hst.y);
            hst.z = fmaf(f1, Bm.z, hst.z);
            hst.w = fmaf(f1, Bm.w, hst.w);
        }
        *(float4*)hp = hst;
        const float a = aprod[bh * NSEG + s];
        cur.x = fmaf(a, cur.x, tmp.x);
        cur.y = fmaf(a, cur.y, tmp.y);
        cur.z = fmaf(a, cur.z, tmp.z);
        cur.w = fmaf(a, cur.w, tmp.w);
    }
}

// ---------------------------------------------------------------------------
// ssd_y v3: C/B/H fragments from global (L2); Gw fp32 in LDS with D folded
// into the diagonal; X^T staged in LDS in two 64-step halves. 2 blocks/CU.
// ---------------------------------------------------------------------------
#define GWF 132
#define XTS 72
__global__ __launch_bounds__(256, 2) void ssd_y(const float* __restrict__ zx,
        const float* __restrict__ Brot, const float* __restrict__ Crot,
        const float4* __restrict__ abg4, const float* __restrict__ hseg,
        const float* __restrict__ Lbuf, const float* __restrict__ Dp,
        float* __restrict__ yb) {
    __shared__ float Gw[128 * GWF];
    __shared__ u16 XTh[64 * XTS];
    __shared__ float Ls[128], gbs[128], gms[128], eLs[128];

    const int blk = blockIdx.x;
    const int seg = blk & (NSEG - 1), bh = blk >> 3;
    const int b = bh >> 5, h = bh & 31;
    const int tid = threadIdx.x;
    const int t0 = seg * SEG;
    const int lane = tid & 63, wave = tid >> 6;
    const int wr = wave >> 1, wc = wave & 1;
    const int lr = lane >> 4, lc = lane & 15;

    if (tid < 128) {
        const int t = t0 + tid;
        const float4 A = abg4[(size_t)bh * LSEQ + t];
        const float Lv = Lbuf[(size_t)bh * LSEQ + t];
        Ls[tid] = Lv;
        gms[tid] = A.z;
        gbs[tid] = (tid < 127) ? A.z + abg4[(size_t)bh * LSEQ + t + 1].w : 0.f;
        eLs[tid] = __expf(Lv);
    }
    __syncthreads();

    const float* Cbase = Crot + ((size_t)bh * LSEQ + t0) * DS;
    const float* Bbase = Brot + ((size_t)bh * LSEQ + t0) * DS;
    const float* Hbase = hseg + ((size_t)(bh * NSEG + seg) * HD) * DS;
    const float* Xbase = zx + ((size_t)b * LSEQ + t0) * DTOT + OFF_X + h * 64;

    f32x4 accP[4][2] = {};
    f32x4 accG[4][4] = {};
    #pragma unroll
    for (int ks = 0; ks < 2; ++ks) {
        const int k0 = ks * 32 + lr * 8;
        s16x8 ch[4], cl4[4], bh4[4], bl4[4], hh2[2];
        #pragma unroll
        for (int f = 0; f < 4; ++f) {
            const int rowc = wr * 64 + f * 16 + lc;
            const float4 c0 = *(const float4*)(Cbase + (size_t)rowc * DS + k0);
            const float4 c1 = *(const float4*)(Cbase + (size_t)rowc * DS + k0 + 4);
            split8(c0, c1, ch[f], cl4[f]);
            const int rowb = wc * 64 + f * 16 + lc;
            const float4 b0 = *(const float4*)(Bbase + (size_t)rowb * DS + k0);
            const float4 b1 = *(const float4*)(Bbase + (size_t)rowb * DS + k0 + 4);
            split8(b0, b1, bh4[f], bl4[f]);
        }
        #pragma unroll
        for (int f = 0; f < 2; ++f) {
            const int rowp = wc * 32 + f * 16 + lc;
            const float4 h0 = *(const float4*)(Hbase + (size_t)rowp * DS + k0);
            const float4 h1 = *(const float4*)(Hbase + (size_t)rowp * DS + k0 + 4);
            cvt8(h0, h1, hh2[f]);
        }
        #pragma unroll
        for (int fm = 0; fm < 4; ++fm) {
            #pragma unroll
            for (int fn = 0; fn < 4; ++fn) {
                accG[fm][fn] = __builtin_amdgcn_mfma_f32_16x16x32_bf16(
                    ch[fm], bh4[fn], accG[fm][fn], 0, 0, 0);
                accG[fm][fn] = __builtin_amdgcn_mfma_f32_16x16x32_bf16(
                    ch[fm], bl4[fn], accG[fm][fn], 0, 0, 0);
                accG[fm][fn] = __builtin_amdgcn_mfma_f32_16x16x32_bf16(
                    cl4[fm], bh4[fn], accG[fm][fn], 0, 0, 0);
            }
            #pragma unroll
            for (int fn = 0; fn < 2; ++fn) {
                accP[fm][fn] = __builtin_amdgcn_mfma_f32_16x16x32_bf16(
                    ch[fm], hh2[fn], accP[fm][fn], 0, 0, 0);
                accP[fm][fn] = __builtin_amdgcn_mfma_f32_16x16x32_bf16(
                    cl4[fm], hh2[fn], accP[fm][fn], 0, 0, 0);
            }
        }
    }

    const float Dh = Dp[h];
    #pragma unroll
    for (int fm = 0; fm < 4; ++fm)
        #pragma unroll
        for (int fn = 0; fn < 4; ++fn)
            #pragma unroll
            for (int jj = 0; jj < 4; ++jj) {
                const int i = wr * 64 + fm * 16 + lr * 4 + jj;
                const int j = wc * 64 + fn * 16 + lc;
                float v;
                if (j < i)       v = accG[fm][fn][jj] * __expf(Ls[i] - Ls[j]) * gbs[j];
                else if (j == i) v = accG[fm][fn][jj] * gms[i] + Dh;
                else             v = 0.f;
                Gw[i * GWF + j] = v;
            }

    f32x4 accY[4][2];
    #pragma unroll
    for (int fm = 0; fm < 4; ++fm)
        #pragma unroll
        for (int fn = 0; fn < 2; ++fn)
            #pragma unroll
            for (int jj = 0; jj < 4; ++jj) {
                const int i = wr * 64 + fm * 16 + lr * 4 + jj;
                accY[fm][fn][jj] = eLs[i] * accP[fm][fn][jj];
            }

#define STAGE_XT(H) {                                                        \
        const int lp = tid >> 2, pq = (tid & 3) * 16;                        \
        const float* xs = Xbase + (size_t)((H) * 64 + lp) * DTOT + pq;       \
        _Pragma("unroll")                                                    \
        for (int i = 0; i < 16; i += 4) {                                    \
            const float4 xv = *(const float4*)(xs + i);                      \
            XTh[(pq + i + 0) * XTS + lp] = (u16)f2bf(xv.x);                  \
            XTh[(pq + i + 1) * XTS + lp] = (u16)f2bf(xv.y);                  \
            XTh[(pq + i + 2) * XTS + lp] = (u16)f2bf(xv.z);                  \
            XTh[(pq + i + 3) * XTS + lp] = (u16)f2bf(xv.w);                  \
        }                                                                    \
    }
    STAGE_XT(0);
    __syncthreads();

    #pragma unroll
    for (int ks = 0; ks < 4; ++ks) {
        if (ks == 2) {
            __syncthreads();
            STAGE_XT(1);
            __syncthreads();
        }
        const int k0 = ks * 32 + lr * 8;
        const int kl = (ks & 1) * 32 + lr * 8;
        s16x8 gh4[4], gl4[4], xf[2];
        #pragma unroll
        for (int f = 0; f < 4; ++f) {
            const int rowi = wr * 64 + f * 16 + lc;
            const float4 g0 = *(const float4*)&Gw[rowi * GWF + k0];
            const float4 g1 = *(const float4*)&Gw[rowi * GWF + k0 + 4];
            split8(g0, g1, gh4[f], gl4[f]);
        }
        #pragma unroll
        for (int f = 0; f < 2; ++f) {
            const int rowp = wc * 32 + f * 16 + lc;
            xf[f] = *(const s16x8*)&XTh[rowp * XTS + kl];
        }
        #pragma unroll
        for (int fm = 0; fm < 4; ++fm)
            #pragma unroll
            for (int fn = 0; fn < 2; ++fn) {
                accY[fm][fn] = __builtin_amdgcn_mfma_f32_16x16x32_bf16(
                    gh4[fm], xf[fn], accY[fm][fn], 0, 0, 0);
                accY[fm][fn] = __builtin_amdgcn_mfma_f32_16x16x32_bf16(
                    gl4[fm], xf[fn], accY[fm][fn], 0, 0, 0);
            }
    }
#undef STAGE_XT

    #pragma unroll
    for (int fm = 0; fm < 4; ++fm)
        #pragma unroll
        for (int fn = 0; fn < 2; ++fn) {
            const int p = wc * 32 + fn * 16 + lc;
            #pragma unroll
            for (int jj = 0; jj < 4; ++jj) {
                const int i = wr * 64 + fm * 16 + lr * 4 + jj;
                yb[((size_t)b * LSEQ + t0 + i) * DIN + h * 64 + p] = accY[fm][fn][jj];
            }
        }
}

// ---------------------------------------------------------------------------
// merged gate+RMS-norm (blocks 0..2047) and out_proj_w conversion (rest).
// ---------------------------------------------------------------------------
__global__ __launch_bounds__(256) void gate_convwo(const float* __restrict__ yb,
        const float* __restrict__ zx, const float* __restrict__ norm_w,
        u16* __restrict__ gnb, const float* __restrict__ wo_src,
        u16* __restrict__ wo_hi) {
    if (blockIdx.x < ROWS) {
        const int bl = blockIdx.x;
        const int tid = threadIdx.x;
        const float* yrow = yb + (size_t)bl * DIN;
        const float* zrow = zx + (size_t)bl * DTOT + OFF_Z;
        float g[8];
        float ss = 0.f;
        #pragma unroll
        for (int i = 0; i < 8; ++i) {
            const int c = tid + i * 256;
            const float yv = yrow[c];
            const float zv = zrow[c];
            const float sg = 1.f / (1.f + expf(-zv));
            const float gv = yv * zv * sg;
            g[i] = gv;
            ss += gv * gv;
        }
        #pragma unroll
        for (int k = 1; k < 64; k <<= 1) ss += __shfl_xor(ss, k);
        __shared__ float wsum[4];
        if ((tid & 63) == 0) wsum[tid >> 6] = ss;
        __syncthreads();
        ss = wsum[0] + wsum[1] + wsum[2] + wsum[3];
        const float sc = rsqrtf(ss * (1.f / 2048.f) + 1e-5f);
        #pragma unroll
        for (int i = 0; i < 8; ++i) {
            const int c = tid + i * 256;
            gnb[(size_t)bl * DIN + c] = (u16)f2bf(g[i] * sc * norm_w[c]);
        }
    } else {
        const size_t i4 = ((size_t)(blockIdx.x - ROWS) * 256 + threadIdx.x) * 4;
        const float4 v = *(const float4*)(wo_src + i4);
        uint2 hw;
        hw.x = pk(v.x, v.y); hw.y = pk(v.z, v.w);
        *(uint2*)(wo_hi + i4) = hw;
    }
}

// ---------------------------------------------------------------------------
extern "C" void kernel_launch(void* const* d_in, const int* in_sizes, int n_in,
                              void* d_out, int out_size, void* d_ws, size_t ws_size,
                              hipStream_t stream) {
    const float* u          = (const float*)d_in[0];
    const float* in_proj_w  = (const float*)d_in[1];
    const float* dt_bias    = (const float*)d_in[2];
    const float* A_log      = (const float*)d_in[3];
    const float* Dp         = (const float*)d_in[4];
    const float* B_norm_w   = (const float*)d_in[5];
    const float* C_norm_w   = (const float*)d_in[6];
    const float* B_bias     = (const float*)d_in[7];
    const float* C_bias     = (const float*)d_in[8];
    const float* norm_w     = (const float*)d_in[9];
    const float* out_proj_w = (const float*)d_in[10];
    float* out = (float*)d_out;

    float* p = (float*)d_ws;
    float* zx    = p; p += (size_t)ROWS * DTOT;
    float* th_cs = p; p += (size_t)ROWS * 1024;   // dead after rot -> hseg
    float* Brot  = p; p += (size_t)ROWS * 2048;   // doubles as bf16 scratch
    float* Crot  = p; p += (size_t)ROWS * 2048;
    float* Bg    = p; p += (size_t)ROWS * 64;     // dead after rot -> aprod/bscale/Lbuf
    float* Cg    = p; p += (size_t)ROWS * 64;     // dead after rot -> wbuf
    float4* abg4 = (float4*)p; p += (size_t)ROWS * NH * 4;
    float* yb    = p; p += (size_t)ROWS * 2048;
    float* hseg   = th_cs;
    float* aprod  = Bg;
    float* bscale = Bg + 512;
    float* Lbuf   = Bg + 2048;
    float* wbuf   = Cg;

    u16* u_bf = (u16*)Brot;
    u16* u_lo = u_bf + (size_t)ROWS * DMODEL;
    u16* w_bf = u_lo + (size_t)ROWS * DMODEL;
    u16* w_lo = w_bf + (size_t)DTOT * DMODEL;
    u16* gn_bf = (u16*)Brot;
    u16* wo_bf = gn_bf + (size_t)ROWS * DIN;

    conv_uw<<<CONV_U_BLOCKS + CONV_W_BLOCKS, 256, 0, stream>>>(
        u, in_proj_w, u_bf, u_lo, w_bf, w_lo);
    mfma_inproj<<<ZX_BLOCKS + R3_BLOCKS, 256, 0, stream>>>(
        u_bf, u_lo, w_bf, w_lo, zx);
    prep_cumsum<<<512 + BB * NH, 256, 0, stream>>>(zx, dt_bias, A_log, B_norm_w,
                                                   C_norm_w, Bg, Cg, abg4, th_cs);
    rot_kernel<<<(ROWS * 1024) / 256, 256, 0, stream>>>(th_cs, Bg, Cg, B_bias, C_bias,
                                                        Brot, Crot);
    wcalc_kernel<<<BB * NH, 64, 0, stream>>>(abg4, wbuf, aprod, bscale, Lbuf);
    hseg_gemm<<<BB * NH * NSEG, 256, 0, stream>>>(zx, Brot, wbuf, hseg);
    scan_fix<<<BB * NH * 4, 256, 0, stream>>>(hseg, aprod, bscale, zx, Brot, abg4);
    ssd_y<<<BB * NH * NSEG, 256, 0, stream>>>(zx, Brot, Crot, abg4, hseg, Lbuf, Dp, yb);
    gate_convwo<<<ROWS + (DMODEL * DIN / 4) / 256, 256, 0, stream>>>(
        yb, zx, norm_w, gn_bf, out_proj_w, wo_bf);
    mfma_gemm_out<<<dim3(DMODEL / 64, ROWS / 128), 256, 0, stream>>>(
        gn_bf, wo_bf, out, DIN, DMODEL);
}

// Round 24
// 174.930 us; speedup vs baseline: 2.0237x; 1.0018x over previous
//
#include <hip/hip_runtime.h>
#include <hip/hip_bf16.h>

// Problem constants
#define DMODEL 1024
#define DIN    2048
#define NH     32
#define HD     64
#define DS     64
#define LSEQ   1024
#define BB     2
#define DTOT   5312           // 2*DIN + 2*64 + 32 + 1024 + 32
#define ROWS   (BB*LSEQ)      // 2048
// column offsets inside zxbcdt
#define OFF_Z   0
#define OFF_X   2048
#define OFF_BR  4096
#define OFF_CR  4160
#define OFF_DT  4224
#define OFF_TH  4256
#define OFF_LAM 5280
#define NZX     4096          // z+x columns: single-pass bf16 MFMA
#define NREM    (DTOT - NZX)  // 1216 cols: 3-pass split-bf16 MFMA
// segmented scan
#define NSEG 8
#define SEG  (LSEQ / NSEG)    // 128

typedef short  s16x8 __attribute__((ext_vector_type(8)));
typedef float  f32x4 __attribute__((ext_vector_type(4)));
typedef unsigned short u16;

__device__ __forceinline__ unsigned int f2bf(float f) {   // RNE f32->bf16 (finite inputs)
    unsigned int u = __float_as_uint(f);
    u += 0x7fffu + ((u >> 16) & 1u);
    return u >> 16;
}
__device__ __forceinline__ unsigned int pk(float x, float y) {
    return f2bf(x) | (f2bf(y) << 16);
}
__device__ __forceinline__ void split1(float v, u16& hi, u16& lo) {
    const unsigned int h = f2bf(v);
    hi = (u16)h;
    lo = (u16)f2bf(v - __uint_as_float(h << 16));
}
__device__ __forceinline__ void split8(const float4 a, const float4 b,
                                       s16x8& hi, s16x8& lo) {
    u16 h_, l_;
    split1(a.x, h_, l_); hi[0] = (short)h_; lo[0] = (short)l_;
    split1(a.y, h_, l_); hi[1] = (short)h_; lo[1] = (short)l_;
    split1(a.z, h_, l_); hi[2] = (short)h_; lo[2] = (short)l_;
    split1(a.w, h_, l_); hi[3] = (short)h_; lo[3] = (short)l_;
    split1(b.x, h_, l_); hi[4] = (short)h_; lo[4] = (short)l_;
    split1(b.y, h_, l_); hi[5] = (short)h_; lo[5] = (short)l_;
    split1(b.z, h_, l_); hi[6] = (short)h_; lo[6] = (short)l_;
    split1(b.w, h_, l_); hi[7] = (short)h_; lo[7] = (short)l_;
}
__device__ __forceinline__ void cvt8(const float4 a, const float4 b, s16x8& hi) {
    hi[0] = (short)f2bf(a.x); hi[1] = (short)f2bf(a.y);
    hi[2] = (short)f2bf(a.z); hi[3] = (short)f2bf(a.w);
    hi[4] = (short)f2bf(b.x); hi[5] = (short)f2bf(b.y);
    hi[6] = (short)f2bf(b.z); hi[7] = (short)f2bf(b.w);
}

// HBM -> LDS direct 16B copy. Dest = wave-uniform base + lane*16 (m104).
typedef const __attribute__((address_space(1))) unsigned int glb_u32;
typedef __attribute__((address_space(3))) unsigned int lds_u32;
__device__ __forceinline__ void gload16(const void* g, void* l) {
    __builtin_amdgcn_global_load_lds((glb_u32*)g, (lds_u32*)l, 16, 0, 0);
}

// XOR swizzles (involutions; source chunk + LDS read index; rule #21).
#define SWZ(row)  (((row) >> 1) & 3)   // 4 chunks/row  (BK=32 tiles)
#define SWZ8(row) (((row) >> 1) & 7)   // 8 chunks/row  (BK=64 tiles)

// ---------------------------------------------------------------------------
// merged conversion kernel: u (blocks 0..2047) and in_proj_w (rest).
// ---------------------------------------------------------------------------
#define CONV_U_BLOCKS (ROWS * DMODEL / 4 / 256)           // 2048
#define CONV_W_BLOCKS ((DTOT * DMODEL / 4) / 256)         // 5312
__global__ __launch_bounds__(256) void conv_uw(const float* __restrict__ usrc,
        const float* __restrict__ wsrc, u16* __restrict__ u_hi,
        u16* __restrict__ u_lo, u16* __restrict__ w_hi, u16* __restrict__ w_lo) {
    const int bid = blockIdx.x;
    if (bid < CONV_U_BLOCKS) {
        const size_t i4 = ((size_t)bid * 256 + threadIdx.x) * 4;
        const float4 v = *(const float4*)(usrc + i4);
        const unsigned int h0 = f2bf(v.x), h1 = f2bf(v.y), h2 = f2bf(v.z), h3 = f2bf(v.w);
        uint2 hw, lw;
        hw.x = h0 | (h1 << 16); hw.y = h2 | (h3 << 16);
        lw.x = pk(v.x - __uint_as_float(h0 << 16), v.y - __uint_as_float(h1 << 16));
        lw.y = pk(v.z - __uint_as_float(h2 << 16), v.w - __uint_as_float(h3 << 16));
        *(uint2*)(u_hi + i4) = hw;
        *(uint2*)(u_lo + i4) = lw;
    } else {
        const size_t i4 = ((size_t)(bid - CONV_U_BLOCKS) * 256 + threadIdx.x) * 4;
        const float4 v = *(const float4*)(wsrc + i4);
        const unsigned int h0 = f2bf(v.x), h1 = f2bf(v.y), h2 = f2bf(v.z), h3 = f2bf(v.w);
        uint2 hw, lw;
        hw.x = h0 | (h1 << 16); hw.y = h2 | (h3 << 16);
        lw.x = pk(v.x - __uint_as_float(h0 << 16), v.y - __uint_as_float(h1 << 16));
        lw.y = pk(v.z - __uint_as_float(h2 << 16), v.w - __uint_as_float(h3 << 16));
        *(uint2*)(w_hi + i4) = hw;
        if ((i4 >> 10) >= NZX)
            *(uint2*)(w_lo + (i4 - (size_t)NZX * DMODEL)) = lw;
    }
}

// ---------------------------------------------------------------------------
// merged in_proj GEMM: blocks 0..511 = z/x tiles (BK=64), 512..815 = rem3.
// z/x branch now uses COUNTED vmcnt (T4) + raw s_barriers instead of
// __syncthreads: prefetch loads stay in flight across the MFMA phase; the
// per-tile vmcnt(0) drain (the measured stall) is removed. rem3 = control.
// ---------------------------------------------------------------------------
#define ZX_BLOCKS 512
#define R3_BLOCKS ((NREM / 64) * (ROWS / 128))   // 19*16 = 304
__global__ __launch_bounds__(256) void mfma_inproj(const u16* __restrict__ u_bf,
        const u16* __restrict__ u_lo, const u16* __restrict__ w_bf,
        const u16* __restrict__ w_lo, float* __restrict__ zx) {
    __shared__ u16 smem[32768];    // 64 KB union
    const int tid = threadIdx.x;
    const int lane = tid & 63, wave = tid >> 6;
    const int wr = wave >> 1, wc = wave & 1;
    const int lr = lane >> 4, lc = lane & 15;

    if (blockIdx.x < ZX_BLOCKS) {
        // ---------------- z/x branch (BK=64, XCD remap, counted vmcnt) -------
        const int bid = blockIdx.x;
        const int kx = bid & 7, lx = bid >> 3;
        const int mt = (kx >> 2) * 8 + (lx >> 3);   // 0..15
        const int nt = (kx & 3) * 8 + (lx & 7);     // 0..31
        const int m0 = mt * 128, n0 = nt * 128;
        const int sr = tid >> 3;
        const int sc = (((tid & 7) ^ ((tid >> 4) & 7)) * 8);
        f32x4 acc[4][4] = {};
        const u16* pA = u_bf + (size_t)(m0 + sr) * DMODEL + sc;
        const u16* pB = w_bf + (size_t)(n0 + sr) * DMODEL + sc;
        u16* Al = smem;              // buf stride 8192 u16
        u16* Bl = smem + 16384;

#define STAGE_ZX(buf, k0) {                                                       \
        gload16(pA + (k0),                       Al + (buf)*8192 + tid*8);        \
        gload16(pA + (k0) + (size_t)32 * DMODEL, Al + (buf)*8192 + tid*8 + 2048); \
        gload16(pA + (k0) + (size_t)64 * DMODEL, Al + (buf)*8192 + tid*8 + 4096); \
        gload16(pA + (k0) + (size_t)96 * DMODEL, Al + (buf)*8192 + tid*8 + 6144); \
        gload16(pB + (k0),                       Bl + (buf)*8192 + tid*8);        \
        gload16(pB + (k0) + (size_t)32 * DMODEL, Bl + (buf)*8192 + tid*8 + 2048); \
        gload16(pB + (k0) + (size_t)64 * DMODEL, Bl + (buf)*8192 + tid*8 + 4096); \
        gload16(pB + (k0) + (size_t)96 * DMODEL, Bl + (buf)*8192 + tid*8 + 6144); }

        STAGE_ZX(0, 0);
        int cur = 0;
        for (int k0 = 0; k0 < DMODEL; k0 += 64) {
            if (k0 + 64 < DMODEL) {
                STAGE_ZX(cur ^ 1, k0 + 64);    // 8 new loads in flight
                // wait for THIS tile's 8 loads (issued last iter); keep 8 newest flying
                asm volatile("s_waitcnt vmcnt(8)" ::: "memory");
            } else {
                asm volatile("s_waitcnt vmcnt(0)" ::: "memory");
            }
            __builtin_amdgcn_s_barrier();      // all waves' cur-tile loads landed
            #pragma unroll
            for (int kk = 0; kk < 2; ++kk) {
                s16x8 af[4], bf[4];
                #pragma unroll
                for (int f = 0; f < 4; ++f) {
                    const int ra = wr * 64 + f * 16 + lc;
                    af[f] = *(const s16x8*)&Al[cur * 8192 + ra * 64 + (((kk * 4 + lr) ^ SWZ8(ra)) * 8)];
                    const int rb = wc * 64 + f * 16 + lc;
                    bf[f] = *(const s16x8*)&Bl[cur * 8192 + rb * 64 + (((kk * 4 + lr) ^ SWZ8(rb)) * 8)];
                }
                #pragma unroll
                for (int fm = 0; fm < 4; ++fm)
                    #pragma unroll
                    for (int fn = 0; fn < 4; ++fn)
                        acc[fm][fn] = __builtin_amdgcn_mfma_f32_16x16x32_bf16(
                            af[fm], bf[fn], acc[fm][fn], 0, 0, 0);
            }
            __builtin_amdgcn_s_barrier();      // reads done before next overwrite
            cur ^= 1;
        }
#undef STAGE_ZX

        #pragma unroll
        for (int fm = 0; fm < 4; ++fm)
            #pragma unroll
            for (int fn = 0; fn < 4; ++fn) {
                const size_t col = n0 + wc * 64 + fn * 16 + lc;
                #pragma unroll
                for (int j = 0; j < 4; ++j) {
                    const size_t row = m0 + wr * 64 + fm * 16 + lr * 4 + j;
                    zx[row * DTOT + col] = acc[fm][fn][j];
                }
            }
    } else {
        // ---------------- rem3 branch (BK=32, 3-pass split; control) --------
        const int rid = blockIdx.x - ZX_BLOCKS;
        const int m0 = (rid / (NREM / 64)) * 128, n0 = (rid % (NREM / 64)) * 64;
        const int sr = tid >> 2;
        const int sc = (((tid & 3) ^ SWZ(tid >> 2)) * 8);
        f32x4 acc[4][2] = {};
        const u16* pAh = u_bf + (size_t)(m0 + sr) * DMODEL + sc;
        const u16* pAl = u_lo + (size_t)(m0 + sr) * DMODEL + sc;
        const u16* pBh = w_bf + (size_t)(NZX + n0 + sr) * DMODEL + sc;
        const u16* pBl = w_lo + (size_t)(n0 + sr) * DMODEL + sc;
        u16* Ah  = smem;             // buf stride 4096 u16
        u16* Alo = smem + 8192;
        u16* Bh  = smem + 16384;     // buf stride 2048 u16
        u16* Blo = smem + 20480;

#define STAGE_R3(buf, k0) {                                                          \
        gload16(pAh + (k0),                       Ah  + (buf)*4096 + tid*8);         \
        gload16(pAh + (k0) + (size_t)64 * DMODEL, Ah  + (buf)*4096 + tid*8 + 2048);  \
        gload16(pAl + (k0),                       Alo + (buf)*4096 + tid*8);         \
        gload16(pAl + (k0) + (size_t)64 * DMODEL, Alo + (buf)*4096 + tid*8 + 2048);  \
        gload16(pBh + (k0),                       Bh  + (buf)*2048 + tid*8);         \
        gload16(pBl + (k0),                       Blo + (buf)*2048 + tid*8); }

        STAGE_R3(0, 0);
        __syncthreads();
        int cur = 0;
        for (int k0 = 0; k0 < DMODEL; k0 += 32) {
            if (k0 + 32 < DMODEL) STAGE_R3(cur ^ 1, k0 + 32);
            s16x8 ahf[4], alf[4], bhf[2], blf[2];
            #pragma unroll
            for (int f = 0; f < 4; ++f) {
                const int ra = wr * 64 + f * 16 + lc;
                const int oa = ra * 32 + ((lr ^ SWZ(ra)) * 8);
                ahf[f] = *(const s16x8*)&Ah[cur * 4096 + oa];
                alf[f] = *(const s16x8*)&Alo[cur * 4096 + oa];
            }
            #pragma unroll
            for (int f = 0; f < 2; ++f) {
                const int rb = wc * 32 + f * 16 + lc;
                const int ob = rb * 32 + ((lr ^ SWZ(rb)) * 8);
                bhf[f] = *(const s16x8*)&Bh[cur * 2048 + ob];
                blf[f] = *(const s16x8*)&Blo[cur * 2048 + ob];
            }
            #pragma unroll
            for (int fm = 0; fm < 4; ++fm)
                #pragma unroll
                for (int fn = 0; fn < 2; ++fn) {
                    acc[fm][fn] = __builtin_amdgcn_mfma_f32_16x16x32_bf16(
                        ahf[fm], bhf[fn], acc[fm][fn], 0, 0, 0);
                    acc[fm][fn] = __builtin_amdgcn_mfma_f32_16x16x32_bf16(
                        ahf[fm], blf[fn], acc[fm][fn], 0, 0, 0);
                    acc[fm][fn] = __builtin_amdgcn_mfma_f32_16x16x32_bf16(
                        alf[fm], bhf[fn], acc[fm][fn], 0, 0, 0);
                }
            __syncthreads();
            cur ^= 1;
        }
#undef STAGE_R3

        #pragma unroll
        for (int fm = 0; fm < 4; ++fm)
            #pragma unroll
            for (int fn = 0; fn < 2; ++fn) {
                const size_t col = NZX + n0 + wc * 32 + fn * 16 + lc;
                #pragma unroll
                for (int j = 0; j < 4; ++j) {
                    const size_t row = m0 + wr * 64 + fm * 16 + lr * 4 + j;
                    zx[row * DTOT + col] = acc[fm][fn][j];
                }
            }
    }
}

// ---------------------------------------------------------------------------
// bf16 MFMA GEMM, 128x64 tile, BK=64: out = gn_bf @ wo_bf^T (LDS 48KB)
// ---------------------------------------------------------------------------
__global__ __launch_bounds__(256) void mfma_gemm_out(const u16* __restrict__ A,
                                                     const u16* __restrict__ B,
                                                     float* __restrict__ C,
                                                     int K, int ldc) {
    __shared__ u16 Als[2][128 * 64];
    __shared__ u16 Bls[2][64 * 64];
    const int tid = threadIdx.x;
    const int m0 = blockIdx.y * 128, n0 = blockIdx.x * 64;
    const int lane = tid & 63, wave = tid >> 6;
    const int wr = wave >> 1, wc = wave & 1;
    const int lr = lane >> 4, lc = lane & 15;
    const int sr = tid >> 3;
    const int sc = (((tid & 7) ^ ((tid >> 4) & 7)) * 8);

    f32x4 acc[4][2] = {};

    const u16* pA = A + (size_t)(m0 + sr) * K + sc;
    const u16* pB = B + (size_t)(n0 + sr) * K + sc;

#define STAGE_OUT(buf, k0) {                                                  \
        gload16(pA + (k0),                   &Als[buf][tid * 8]);             \
        gload16(pA + (k0) + (size_t)32 * K,  &Als[buf][tid * 8 + 2048]);      \
        gload16(pA + (k0) + (size_t)64 * K,  &Als[buf][tid * 8 + 4096]);      \
        gload16(pA + (k0) + (size_t)96 * K,  &Als[buf][tid * 8 + 6144]);      \
        gload16(pB + (k0),                   &Bls[buf][tid * 8]);             \
        gload16(pB + (k0) + (size_t)32 * K,  &Bls[buf][tid * 8 + 2048]); }

    STAGE_OUT(0, 0);
    __syncthreads();
    int cur = 0;
    for (int k0 = 0; k0 < K; k0 += 64) {
        if (k0 + 64 < K) STAGE_OUT(cur ^ 1, k0 + 64);
        #pragma unroll
        for (int kk = 0; kk < 2; ++kk) {
            s16x8 af[4], bf[2];
            #pragma unroll
            for (int f = 0; f < 4; ++f) {
                const int ra = wr * 64 + f * 16 + lc;
                af[f] = *(const s16x8*)&Als[cur][ra * 64 + (((kk * 4 + lr) ^ SWZ8(ra)) * 8)];
            }
            #pragma unroll
            for (int f = 0; f < 2; ++f) {
                const int rb = wc * 32 + f * 16 + lc;
                bf[f] = *(const s16x8*)&Bls[cur][rb * 64 + (((kk * 4 + lr) ^ SWZ8(rb)) * 8)];
            }
            #pragma unroll
            for (int fm = 0; fm < 4; ++fm)
                #pragma unroll
                for (int fn = 0; fn < 2; ++fn)
                    acc[fm][fn] = __builtin_amdgcn_mfma_f32_16x16x32_bf16(
                        af[fm], bf[fn], acc[fm][fn], 0, 0, 0);
        }
        __syncthreads();
        cur ^= 1;
    }
#undef STAGE_OUT

    #pragma unroll
    for (int fm = 0; fm < 4; ++fm)
        #pragma unroll
        for (int fn = 0; fn < 2; ++fn) {
            const size_t col = n0 + wc * 32 + fn * 16 + lc;
            #pragma unroll
            for (int j = 0; j < 4; ++j) {
                const size_t row = m0 + wr * 64 + fm * 16 + lr * 4 + j;
                C[row * (size_t)ldc + col] = acc[fm][fn][j];
            }
        }
}

// ---------------------------------------------------------------------------
// merged prep + cumsum (both only READ zx; outputs disjoint -> race-free).
// ---------------------------------------------------------------------------
__global__ __launch_bounds__(256) void prep_cumsum(const float* __restrict__ zx,
        const float* __restrict__ dt_bias, const float* __restrict__ A_log,
        const float* __restrict__ B_norm_w, const float* __restrict__ C_norm_w,
        float* __restrict__ Bg, float* __restrict__ Cg,
        float4* __restrict__ abg4, float* __restrict__ th_cs) {
    __shared__ float sums[8][33];
    const int bid = blockIdx.x;
    const int tid = threadIdx.x;
    if (bid < 512) {
        const int bl = bid * 4 + (tid >> 6);
        const int t  = tid & 63;
        const int b = bl >> 10, l = bl & (LSEQ - 1);
        const float* row = zx + (size_t)bl * DTOT;
        const float br = row[OFF_BR + t];
        const float cr = row[OFF_CR + t];
        float ssb = br * br, ssc = cr * cr;
        #pragma unroll
        for (int k = 1; k < 64; k <<= 1) { ssb += __shfl_xor(ssb, k); ssc += __shfl_xor(ssc, k); }
        const float scB = rsqrtf(ssb * (1.f / 64.f) + 1e-5f);
        const float scC = rsqrtf(ssc * (1.f / 64.f) + 1e-5f);
        Bg[(size_t)bl * 64 + t] = br * scB * B_norm_w[t];
        Cg[(size_t)bl * 64 + t] = cr * scC * C_norm_w[t];
        if (t < NH) {
            const float dtr = row[OFF_DT + t] + dt_bias[t];
            const float dt  = (dtr > 20.f) ? dtr : log1pf(expf(dtr));
            const float lamr = row[OFF_LAM + t];
            const float lam  = 1.f / (1.f + expf(-lamr));
            const float Ah   = -expf(A_log[t]);
            const float al   = expf(dt * Ah);
            const float bp   = (1.f - lam) * dt;        // beta' = b/a
            const size_t o = ((size_t)b * NH + t) * LSEQ + l;
            abg4[o] = make_float4(al, bp * al, lam * dt, bp);
        }
    } else {
        const int bh = bid - 512;
        const int b = bh >> 5, h = bh & 31;
        const int d = tid & 31, seg = tid >> 5;
        const float* base = zx + (size_t)b * LSEQ * DTOT + OFF_TH + h * 32 + d;
        float* out = th_cs + (size_t)b * LSEQ * 1024 + h * 32 + d;
        const int l0 = seg * 128;
        float s = 0.f;
        #pragma unroll 4
        for (int i = 0; i < 128; ++i) s += base[(size_t)(l0 + i) * DTOT];
        sums[seg][d] = s;
        __syncthreads();
        float acc = 0.f;
        for (int s2 = 0; s2 < seg; ++s2) acc += sums[s2][d];
        #pragma unroll 4
        for (int i = 0; i < 128; ++i) {
            acc += base[(size_t)(l0 + i) * DTOT];
            out[(size_t)(l0 + i) * 1024] = acc;
        }
    }
}

// ---------------------------------------------------------------------------
// rot: Bh/Ch = rot(broadcast(Bg/Cg)+bias). Brot/Crot layout (B,NH,L,DS).
// ---------------------------------------------------------------------------
__global__ __launch_bounds__(256) void rot_kernel(const float* __restrict__ th_cs,
        const float* __restrict__ Bg, const float* __restrict__ Cg,
        const float* __restrict__ B_bias, const float* __restrict__ C_bias,
        float* __restrict__ Brot, float* __restrict__ Crot) {
    const size_t idx = (size_t)blockIdx.x * 256 + threadIdx.x;
    const int j = (int)(idx & 31);
    const int h = (int)((idx >> 5) & 31);
    const size_t bl = idx >> 10;
    const int l = (int)(bl & (LSEQ - 1));
    const int b = (int)(bl >> 10);
    const float th = th_cs[idx];
    float s, c;
    sincosf(th, &s, &c);
    float v1 = Bg[bl * 64 + j]      + B_bias[h * 64 + j];
    float v2 = Bg[bl * 64 + 32 + j] + B_bias[h * 64 + 32 + j];
    const size_t ob = ((size_t)(b * NH + h) * LSEQ + l) * DS + j;
    Brot[ob]      = v1 * c - v2 * s;
    Brot[ob + 32] = v1 * s + v2 * c;
    v1 = Cg[bl * 64 + j]      + C_bias[h * 64 + j];
    v2 = Cg[bl * 64 + 32 + j] + C_bias[h * 64 + 32 + j];
    Crot[ob]      = v1 * c - v2 * s;
    Crot[ob + 32] = v1 * s + v2 * c;
}

// ---------------------------------------------------------------------------
// wcalc: per (b,h,seg): within-seg log-cumsum of alpha; emits
//   wbuf[t], Lbuf[t], aprod[s], bscale[s]  (round 13/15 derivation)
// ---------------------------------------------------------------------------
__global__ __launch_bounds__(64) void wcalc_kernel(const float4* __restrict__ abg4,
        float* __restrict__ wbuf, float* __restrict__ aprod,
        float* __restrict__ bscale, float* __restrict__ Lbuf) {
    const int bh = blockIdx.x;
    const int lane = threadIdx.x;
    const int seg = lane >> 3, sub = lane & 7;
    const int t0 = seg * SEG;
    const int sbase = t0 + sub * 16;
    const float4* ab = abg4 + (size_t)bh * LSEQ;

    float part = 0.f;
    #pragma unroll
    for (int i = 0; i < 16; ++i) part += logf(ab[sbase + i].x);
    float incl = part;
    #pragma unroll
    for (int d = 1; d < 8; d <<= 1) {
        const float v = __shfl_up(incl, d, 8);
        if (sub >= d) incl += v;
    }
    const float LE = __shfl(incl, 7, 8);
    float Lrun = incl - part;                // exclusive prefix

    for (int i = 0; i < 16; ++i) {
        const int s = sbase + i;
        const float4 A = ab[s];
        Lrun += logf(A.x);
        Lbuf[(size_t)bh * LSEQ + s] = Lrun;
        float w;
        if ((s & (SEG - 1)) == (SEG - 1)) w = A.z;
        else w = __expf(LE - Lrun) * (A.z + ab[s + 1].w);
        wbuf[(size_t)bh * LSEQ + s] = w;
    }
    if (sub == 0) {
        aprod[bh * NSEG + seg] = __expf(LE);
        bscale[bh * NSEG + seg] = (seg > 0) ? __expf(LE) * ab[t0].w : 0.f;
    }
}

// ---------------------------------------------------------------------------
// hseg_gemm: h_local_end[p,n] = sum_s wbuf_s * x_s[p] * B_s[n] (split-bf16 3-pass)
// ---------------------------------------------------------------------------
#define WK 136
__global__ __launch_bounds__(256) void hseg_gemm(const float* __restrict__ zx,
        const float* __restrict__ Brot, const float* __restrict__ wbuf,
        float* __restrict__ hseg) {
    __shared__ u16 XH[64][WK], XL[64][WK], BHs[64][WK], BLs[64][WK];
    const int blk = blockIdx.x;
    const int seg = blk & (NSEG - 1), bh = blk >> 3;
    const int b = bh >> 5, h = bh & 31;
    const int tid = threadIdx.x;

    {
        const int sIdx = tid >> 1, half = tid & 1;
        const int t = seg * SEG + sIdx;
        const float wv = wbuf[(size_t)bh * LSEQ + t];
        const float* xsrc = zx + ((size_t)b * LSEQ + t) * DTOT + OFF_X + h * 64 + half * 32;
        const float* bsrc = Brot + ((size_t)bh * LSEQ + t) * DS + half * 32;
        #pragma unroll
        for (int i = 0; i < 32; i += 4) {
            const float4 xv = *(const float4*)(xsrc + i);
            const float4 bv = *(const float4*)(bsrc + i);
            const int p0 = half * 32 + i;
            u16 hi, lo;
            split1(xv.x * wv, hi, lo); XH[p0 + 0][sIdx] = hi; XL[p0 + 0][sIdx] = lo;
            split1(xv.y * wv, hi, lo); XH[p0 + 1][sIdx] = hi; XL[p0 + 1][sIdx] = lo;
            split1(xv.z * wv, hi, lo); XH[p0 + 2][sIdx] = hi; XL[p0 + 2][sIdx] = lo;
            split1(xv.w * wv, hi, lo); XH[p0 + 3][sIdx] = hi; XL[p0 + 3][sIdx] = lo;
            split1(bv.x, hi, lo); BHs[p0 + 0][sIdx] = hi; BLs[p0 + 0][sIdx] = lo;
            split1(bv.y, hi, lo); BHs[p0 + 1][sIdx] = hi; BLs[p0 + 1][sIdx] = lo;
            split1(bv.z, hi, lo); BHs[p0 + 2][sIdx] = hi; BLs[p0 + 2][sIdx] = lo;
            split1(bv.w, hi, lo); BHs[p0 + 3][sIdx] = hi; BLs[p0 + 3][sIdx] = lo;
        }
    }
    __syncthreads();

    const int lane = tid & 63, wave = tid >> 6;
    const int wR = wave >> 1, wC = wave & 1;
    const int lr = lane >> 4, lc = lane & 15;

    f32x4 acc[2][2] = {};
    #pragma unroll
    for (int ks = 0; ks < 4; ++ks) {
        const int k0 = ks * 32;
        s16x8 xh[2], xl[2], bhf[2], blf[2];
        #pragma unroll
        for (int f = 0; f < 2; ++f) {
            const int pr = wR * 32 + f * 16 + lc;
            xh[f] = *(const s16x8*)&XH[pr][k0 + lr * 8];
            xl[f] = *(const s16x8*)&XL[pr][k0 + lr * 8];
            const int nr = wC * 32 + f * 16 + lc;
            bhf[f] = *(const s16x8*)&BHs[nr][k0 + lr * 8];
            blf[f] = *(const s16x8*)&BLs[nr][k0 + lr * 8];
        }
        #pragma unroll
        for (int fm = 0; fm < 2; ++fm)
            #pragma unroll
            for (int fn = 0; fn < 2; ++fn) {
                acc[fm][fn] = __builtin_amdgcn_mfma_f32_16x16x32_bf16(
                    xh[fm], bhf[fn], acc[fm][fn], 0, 0, 0);
                acc[fm][fn] = __builtin_amdgcn_mfma_f32_16x16x32_bf16(
                    xh[fm], blf[fn], acc[fm][fn], 0, 0, 0);
                acc[fm][fn] = __builtin_amdgcn_mfma_f32_16x16x32_bf16(
                    xl[fm], bhf[fn], acc[fm][fn], 0, 0, 0);
            }
    }

    float* hp = hseg + ((size_t)(bh * NSEG + seg) * HD) * DS;
    #pragma unroll
    for (int fm = 0; fm < 2; ++fm)
        #pragma unroll
        for (int fn = 0; fn < 2; ++fn) {
            const int n = wC * 32 + fn * 16 + lc;
            #pragma unroll
            for (int j = 0; j < 4; ++j) {
                const int p = wR * 32 + fm * 16 + lr * 4 + j;
                hp[p * DS + n] = acc[fm][fn][j];
            }
        }
}

// ---------------------------------------------------------------------------
// scan_fix: sequential over segments -> hseg becomes hstar per segment.
// ---------------------------------------------------------------------------
__global__ __launch_bounds__(256) void scan_fix(float* __restrict__ hseg,
        const float* __restrict__ aprod, const float* __restrict__ bscale,
        const float* __restrict__ zx, const float* __restrict__ Brot,
        const float4* __restrict__ abg4) {
    const int blk = blockIdx.x;          // (b,h,ptile): 256
    const int ptile = blk & 3, h = (blk >> 2) & 31, b = blk >> 7;
    const int tid = threadIdx.x;
    const int pl = tid >> 4, ng = tid & 15;
    const int p = ptile * 16 + pl;
    const int n0 = ng * 4;
    const size_t bh = (size_t)b * NH + h;

    float4 cur = make_float4(0.f, 0.f, 0.f, 0.f);
    #pragma unroll
    for (int s = 0; s < NSEG; ++s) {
        float* hp = hseg + (((bh * NSEG + s) * HD + p) * DS + n0);
        float4 tmp = *(const float4*)hp;     // local h_end (no boundary)
        float4 hst = cur;                    // hstar = h_start (+ r1 below)
        if (s > 0) {
            const float bs = bscale[bh * NSEG + s];          // aprod*beta'
            const float bp0 = abg4[bh * LSEQ + s * SEG].w;   // beta'_{t0}
            const int tm1 = s * SEG - 1;
            const float4 Bm = *(const float4*)(Brot + ((size_t)bh * LSEQ + tm1) * DS + n0);
            const float xm = zx[((size_t)b * LSEQ + tm1) * DTOT + OFF_X + h * HD + p];
            const float fb = bs * xm;
            const float f1 = bp0 * xm;
            tmp.x = fmaf(fb, Bm.x, tmp.x);
            tmp.y = fmaf(fb, Bm.y, tmp.y);
            tmp.z = fmaf(fb, Bm.z, tmp.z);
            tmp.w = fmaf(fb, Bm.w, tmp.w);
            hst.x = fmaf(f1, Bm.x, hst.x);
            hst.y = fmaf(f1, Bm.y, hst.y);
            hst.z = fmaf(f1, Bm.z, hst.z);
            hst.w = fmaf(f1, Bm.w, hst.w);
        }
        *(float4*)hp = hst;
        const float a = aprod[bh * NSEG + s];
        cur.x = fmaf(a, cur.x, tmp.x);
        cur.y = fmaf(a, cur.y, tmp.y);
        cur.z = fmaf(a, cur.z, tmp.z);
        cur.w = fmaf(a, cur.w, tmp.w);
    }
}

// ---------------------------------------------------------------------------
// ssd_y v3: C/B/H fragments from global (L2); Gw fp32 in LDS with D folded
// into the diagonal; X^T staged in LDS in two 64-step halves. 2 blocks/CU.
// ---------------------------------------------------------------------------
#define GWF 132
#define XTS 72
__global__ __launch_bounds__(256, 2) void ssd_y(const float* __restrict__ zx,
        const float* __restrict__ Brot, const float* __restrict__ Crot,
        const float4* __restrict__ abg4, const float* __restrict__ hseg,
        const float* __restrict__ Lbuf, const float* __restrict__ Dp,
        float* __restrict__ yb) {
    __shared__ float Gw[128 * GWF];
    __shared__ u16 XTh[64 * XTS];
    __shared__ float Ls[128], gbs[128], gms[128], eLs[128];

    const int blk = blockIdx.x;
    const int seg = blk & (NSEG - 1), bh = blk >> 3;
    const int b = bh >> 5, h = bh & 31;
    const int tid = threadIdx.x;
    const int t0 = seg * SEG;
    const int lane = tid & 63, wave = tid >> 6;
    const int wr = wave >> 1, wc = wave & 1;
    const int lr = lane >> 4, lc = lane & 15;

    if (tid < 128) {
        const int t = t0 + tid;
        const float4 A = abg4[(size_t)bh * LSEQ + t];
        const float Lv = Lbuf[(size_t)bh * LSEQ + t];
        Ls[tid] = Lv;
        gms[tid] = A.z;
        gbs[tid] = (tid < 127) ? A.z + abg4[(size_t)bh * LSEQ + t + 1].w : 0.f;
        eLs[tid] = __expf(Lv);
    }
    __syncthreads();

    const float* Cbase = Crot + ((size_t)bh * LSEQ + t0) * DS;
    const float* Bbase = Brot + ((size_t)bh * LSEQ + t0) * DS;
    const float* Hbase = hseg + ((size_t)(bh * NSEG + seg) * HD) * DS;
    const float* Xbase = zx + ((size_t)b * LSEQ + t0) * DTOT + OFF_X + h * 64;

    f32x4 accP[4][2] = {};
    f32x4 accG[4][4] = {};
    #pragma unroll
    for (int ks = 0; ks < 2; ++ks) {
        const int k0 = ks * 32 + lr * 8;
        s16x8 ch[4], cl4[4], bh4[4], bl4[4], hh2[2];
        #pragma unroll
        for (int f = 0; f < 4; ++f) {
            const int rowc = wr * 64 + f * 16 + lc;
            const float4 c0 = *(const float4*)(Cbase + (size_t)rowc * DS + k0);
            const float4 c1 = *(const float4*)(Cbase + (size_t)rowc * DS + k0 + 4);
            split8(c0, c1, ch[f], cl4[f]);
            const int rowb = wc * 64 + f * 16 + lc;
            const float4 b0 = *(const float4*)(Bbase + (size_t)rowb * DS + k0);
            const float4 b1 = *(const float4*)(Bbase + (size_t)rowb * DS + k0 + 4);
            split8(b0, b1, bh4[f], bl4[f]);
        }
        #pragma unroll
        for (int f = 0; f < 2; ++f) {
            const int rowp = wc * 32 + f * 16 + lc;
            const float4 h0 = *(const float4*)(Hbase + (size_t)rowp * DS + k0);
            const float4 h1 = *(const float4*)(Hbase + (size_t)rowp * DS + k0 + 4);
            cvt8(h0, h1, hh2[f]);
        }
        #pragma unroll
        for (int fm = 0; fm < 4; ++fm) {
            #pragma unroll
            for (int fn = 0; fn < 4; ++fn) {
                accG[fm][fn] = __builtin_amdgcn_mfma_f32_16x16x32_bf16(
                    ch[fm], bh4[fn], accG[fm][fn], 0, 0, 0);
                accG[fm][fn] = __builtin_amdgcn_mfma_f32_16x16x32_bf16(
                    ch[fm], bl4[fn], accG[fm][fn], 0, 0, 0);
                accG[fm][fn] = __builtin_amdgcn_mfma_f32_16x16x32_bf16(
                    cl4[fm], bh4[fn], accG[fm][fn], 0, 0, 0);
            }
            #pragma unroll
            for (int fn = 0; fn < 2; ++fn) {
                accP[fm][fn] = __builtin_amdgcn_mfma_f32_16x16x32_bf16(
                    ch[fm], hh2[fn], accP[fm][fn], 0, 0, 0);
                accP[fm][fn] = __builtin_amdgcn_mfma_f32_16x16x32_bf16(
                    cl4[fm], hh2[fn], accP[fm][fn], 0, 0, 0);
            }
        }
    }

    const float Dh = Dp[h];
    #pragma unroll
    for (int fm = 0; fm < 4; ++fm)
        #pragma unroll
        for (int fn = 0; fn < 4; ++fn)
            #pragma unroll
            for (int jj = 0; jj < 4; ++jj) {
                const int i = wr * 64 + fm * 16 + lr * 4 + jj;
                const int j = wc * 64 + fn * 16 + lc;
                float v;
                if (j < i)       v = accG[fm][fn][jj] * __expf(Ls[i] - Ls[j]) * gbs[j];
                else if (j == i) v = accG[fm][fn][jj] * gms[i] + Dh;
                else             v = 0.f;
                Gw[i * GWF + j] = v;
            }

    f32x4 accY[4][2];
    #pragma unroll
    for (int fm = 0; fm < 4; ++fm)
        #pragma unroll
        for (int fn = 0; fn < 2; ++fn)
            #pragma unroll
            for (int jj = 0; jj < 4; ++jj) {
                const int i = wr * 64 + fm * 16 + lr * 4 + jj;
                accY[fm][fn][jj] = eLs[i] * accP[fm][fn][jj];
            }

#define STAGE_XT(H) {                                                        \
        const int lp = tid >> 2, pq = (tid & 3) * 16;                        \
        const float* xs = Xbase + (size_t)((H) * 64 + lp) * DTOT + pq;       \
        _Pragma("unroll")                                                    \
        for (int i = 0; i < 16; i += 4) {                                    \
            const float4 xv = *(const float4*)(xs + i);                      \
            XTh[(pq + i + 0) * XTS + lp] = (u16)f2bf(xv.x);                  \
            XTh[(pq + i + 1) * XTS + lp] = (u16)f2bf(xv.y);                  \
            XTh[(pq + i + 2) * XTS + lp] = (u16)f2bf(xv.z);                  \
            XTh[(pq + i + 3) * XTS + lp] = (u16)f2bf(xv.w);                  \
        }                                                                    \
    }
    STAGE_XT(0);
    __syncthreads();

    #pragma unroll
    for (int ks = 0; ks < 4; ++ks) {
        if (ks == 2) {
            __syncthreads();
            STAGE_XT(1);
            __syncthreads();
        }
        const int k0 = ks * 32 + lr * 8;
        const int kl = (ks & 1) * 32 + lr * 8;
        s16x8 gh4[4], gl4[4], xf[2];
        #pragma unroll
        for (int f = 0; f < 4; ++f) {
            const int rowi = wr * 64 + f * 16 + lc;
            const float4 g0 = *(const float4*)&Gw[rowi * GWF + k0];
            const float4 g1 = *(const float4*)&Gw[rowi * GWF + k0 + 4];
            split8(g0, g1, gh4[f], gl4[f]);
        }
        #pragma unroll
        for (int f = 0; f < 2; ++f) {
            const int rowp = wc * 32 + f * 16 + lc;
            xf[f] = *(const s16x8*)&XTh[rowp * XTS + kl];
        }
        #pragma unroll
        for (int fm = 0; fm < 4; ++fm)
            #pragma unroll
            for (int fn = 0; fn < 2; ++fn) {
                accY[fm][fn] = __builtin_amdgcn_mfma_f32_16x16x32_bf16(
                    gh4[fm], xf[fn], accY[fm][fn], 0, 0, 0);
                accY[fm][fn] = __builtin_amdgcn_mfma_f32_16x16x32_bf16(
                    gl4[fm], xf[fn], accY[fm][fn], 0, 0, 0);
            }
    }
#undef STAGE_XT

    #pragma unroll
    for (int fm = 0; fm < 4; ++fm)
        #pragma unroll
        for (int fn = 0; fn < 2; ++fn) {
            const int p = wc * 32 + fn * 16 + lc;
            #pragma unroll
            for (int jj = 0; jj < 4; ++jj) {
                const int i = wr * 64 + fm * 16 + lr * 4 + jj;
                yb[((size_t)b * LSEQ + t0 + i) * DIN + h * 64 + p] = accY[fm][fn][jj];
            }
        }
}

// ---------------------------------------------------------------------------
// merged gate+RMS-norm (blocks 0..2047) and out_proj_w conversion (rest).
// ---------------------------------------------------------------------------
__global__ __launch_bounds__(256) void gate_convwo(const float* __restrict__ yb,
        const float* __restrict__ zx, const float* __restrict__ norm_w,
        u16* __restrict__ gnb, const float* __restrict__ wo_src,
        u16* __restrict__ wo_hi) {
    if (blockIdx.x < ROWS) {
        const int bl = blockIdx.x;
        const int tid = threadIdx.x;
        const float* yrow = yb + (size_t)bl * DIN;
        const float* zrow = zx + (size_t)bl * DTOT + OFF_Z;
        float g[8];
        float ss = 0.f;
        #pragma unroll
        for (int i = 0; i < 8; ++i) {
            const int c = tid + i * 256;
            const float yv = yrow[c];
            const float zv = zrow[c];
            const float sg = 1.f / (1.f + expf(-zv));
            const float gv = yv * zv * sg;
            g[i] = gv;
            ss += gv * gv;
        }
        #pragma unroll
        for (int k = 1; k < 64; k <<= 1) ss += __shfl_xor(ss, k);
        __shared__ float wsum[4];
        if ((tid & 63) == 0) wsum[tid >> 6] = ss;
        __syncthreads();
        ss = wsum[0] + wsum[1] + wsum[2] + wsum[3];
        const float sc = rsqrtf(ss * (1.f / 2048.f) + 1e-5f);
        #pragma unroll
        for (int i = 0; i < 8; ++i) {
            const int c = tid + i * 256;
            gnb[(size_t)bl * DIN + c] = (u16)f2bf(g[i] * sc * norm_w[c]);
        }
    } else {
        const size_t i4 = ((size_t)(blockIdx.x - ROWS) * 256 + threadIdx.x) * 4;
        const float4 v = *(const float4*)(wo_src + i4);
        uint2 hw;
        hw.x = pk(v.x, v.y); hw.y = pk(v.z, v.w);
        *(uint2*)(wo_hi + i4) = hw;
    }
}

// ---------------------------------------------------------------------------
extern "C" void kernel_launch(void* const* d_in, const int* in_sizes, int n_in,
                              void* d_out, int out_size, void* d_ws, size_t ws_size,
                              hipStream_t stream) {
    const float* u          = (const float*)d_in[0];
    const float* in_proj_w  = (const float*)d_in[1];
    const float* dt_bias    = (const float*)d_in[2];
    const float* A_log      = (const float*)d_in[3];
    const float* Dp         = (const float*)d_in[4];
    const float* B_norm_w   = (const float*)d_in[5];
    const float* C_norm_w   = (const float*)d_in[6];
    const float* B_bias     = (const float*)d_in[7];
    const float* C_bias     = (const float*)d_in[8];
    const float* norm_w     = (const float*)d_in[9];
    const float* out_proj_w = (const float*)d_in[10];
    float* out = (float*)d_out;

    float* p = (float*)d_ws;
    float* zx    = p; p += (size_t)ROWS * DTOT;
    float* th_cs = p; p += (size_t)ROWS * 1024;   // dead after rot -> hseg
    float* Brot  = p; p += (size_t)ROWS * 2048;   // doubles as bf16 scratch
    float* Crot  = p; p += (size_t)ROWS * 2048;
    float* Bg    = p; p += (size_t)ROWS * 64;     // dead after rot -> aprod/bscale/Lbuf
    float* Cg    = p; p += (size_t)ROWS * 64;     // dead after rot -> wbuf
    float4* abg4 = (float4*)p; p += (size_t)ROWS * NH * 4;
    float* yb    = p; p += (size_t)ROWS * 2048;
    float* hseg   = th_cs;
    float* aprod  = Bg;
    float* bscale = Bg + 512;
    float* Lbuf   = Bg + 2048;
    float* wbuf   = Cg;

    u16* u_bf = (u16*)Brot;
    u16* u_lo = u_bf + (size_t)ROWS * DMODEL;
    u16* w_bf = u_lo + (size_t)ROWS * DMODEL;
    u16* w_lo = w_bf + (size_t)DTOT * DMODEL;
    u16* gn_bf = (u16*)Brot;
    u16* wo_bf = gn_bf + (size_t)ROWS * DIN;

    conv_uw<<<CONV_U_BLOCKS + CONV_W_BLOCKS, 256, 0, stream>>>(
        u, in_proj_w, u_bf, u_lo, w_bf, w_lo);
    mfma_inproj<<<ZX_BLOCKS + R3_BLOCKS, 256, 0, stream>>>(
        u_bf, u_lo, w_bf, w_lo, zx);
    prep_cumsum<<<512 + BB * NH, 256, 0, stream>>>(zx, dt_bias, A_log, B_norm_w,
                                                   C_norm_w, Bg, Cg, abg4, th_cs);
    rot_kernel<<<(ROWS * 1024) / 256, 256, 0, stream>>>(th_cs, Bg, Cg, B_bias, C_bias,
                                                        Brot, Crot);
    wcalc_kernel<<<BB * NH, 64, 0, stream>>>(abg4, wbuf, aprod, bscale, Lbuf);
    hseg_gemm<<<BB * NH * NSEG, 256, 0, stream>>>(zx, Brot, wbuf, hseg);
    scan_fix<<<BB * NH * 4, 256, 0, stream>>>(hseg, aprod, bscale, zx, Brot, abg4);
    ssd_y<<<BB * NH * NSEG, 256, 0, stream>>>(zx, Brot, Crot, abg4, hseg, Lbuf, Dp, yb);
    gate_convwo<<<ROWS + (DMODEL * DIN / 4) / 256, 256, 0, stream>>>(
        yb, zx, norm_w, gn_bf, out_proj_w, wo_bf);
    mfma_gemm_out<<<dim3(DMODEL / 64, ROWS / 128), 256, 0, stream>>>(
        gn_bf, wo_bf, out, DIN, DMODEL);
}

// Round 25
// 172.958 us; speedup vs baseline: 2.0468x; 1.0114x over previous
//
#include <hip/hip_runtime.h>
#include <hip/hip_bf16.h>

// Problem constants
#define DMODEL 1024
#define DIN    2048
#define NH     32
#define HD     64
#define DS     64
#define LSEQ   1024
#define BB     2
#define DTOT   5312           // 2*DIN + 2*64 + 32 + 1024 + 32
#define ROWS   (BB*LSEQ)      // 2048
// column offsets inside zxbcdt
#define OFF_Z   0
#define OFF_X   2048
#define OFF_BR  4096
#define OFF_CR  4160
#define OFF_DT  4224
#define OFF_TH  4256
#define OFF_LAM 5280
#define NZX     4096          // z+x columns: single-pass bf16 MFMA
#define NREM    (DTOT - NZX)  // 1216 cols: 3-pass split-bf16 MFMA
// segmented scan
#define NSEG 8
#define SEG  (LSEQ / NSEG)    // 128

typedef short  s16x8 __attribute__((ext_vector_type(8)));
typedef float  f32x4 __attribute__((ext_vector_type(4)));
typedef unsigned short u16;

__device__ __forceinline__ unsigned int f2bf(float f) {   // RNE f32->bf16 (finite inputs)
    unsigned int u = __float_as_uint(f);
    u += 0x7fffu + ((u >> 16) & 1u);
    return u >> 16;
}
__device__ __forceinline__ unsigned int pk(float x, float y) {
    return f2bf(x) | (f2bf(y) << 16);
}
__device__ __forceinline__ void split1(float v, u16& hi, u16& lo) {
    const unsigned int h = f2bf(v);
    hi = (u16)h;
    lo = (u16)f2bf(v - __uint_as_float(h << 16));
}
__device__ __forceinline__ void split8(const float4 a, const float4 b,
                                       s16x8& hi, s16x8& lo) {
    u16 h_, l_;
    split1(a.x, h_, l_); hi[0] = (short)h_; lo[0] = (short)l_;
    split1(a.y, h_, l_); hi[1] = (short)h_; lo[1] = (short)l_;
    split1(a.z, h_, l_); hi[2] = (short)h_; lo[2] = (short)l_;
    split1(a.w, h_, l_); hi[3] = (short)h_; lo[3] = (short)l_;
    split1(b.x, h_, l_); hi[4] = (short)h_; lo[4] = (short)l_;
    split1(b.y, h_, l_); hi[5] = (short)h_; lo[5] = (short)l_;
    split1(b.z, h_, l_); hi[6] = (short)h_; lo[6] = (short)l_;
    split1(b.w, h_, l_); hi[7] = (short)h_; lo[7] = (short)l_;
}
__device__ __forceinline__ void cvt8(const float4 a, const float4 b, s16x8& hi) {
    hi[0] = (short)f2bf(a.x); hi[1] = (short)f2bf(a.y);
    hi[2] = (short)f2bf(a.z); hi[3] = (short)f2bf(a.w);
    hi[4] = (short)f2bf(b.x); hi[5] = (short)f2bf(b.y);
    hi[6] = (short)f2bf(b.z); hi[7] = (short)f2bf(b.w);
}

// HBM -> LDS direct 16B copy. Dest = wave-uniform base + lane*16 (m104).
typedef const __attribute__((address_space(1))) unsigned int glb_u32;
typedef __attribute__((address_space(3))) unsigned int lds_u32;
__device__ __forceinline__ void gload16(const void* g, void* l) {
    __builtin_amdgcn_global_load_lds((glb_u32*)g, (lds_u32*)l, 16, 0, 0);
}

// XOR swizzles (involutions; source chunk + LDS read index; rule #21).
#define SWZ(row)  (((row) >> 1) & 3)   // 4 chunks/row  (BK=32 tiles)
#define SWZ8(row) (((row) >> 1) & 7)   // 8 chunks/row  (BK=64 tiles)

// ---------------------------------------------------------------------------
// merged conversion kernel: u (blocks 0..2047) and in_proj_w (rest).
// ---------------------------------------------------------------------------
#define CONV_U_BLOCKS (ROWS * DMODEL / 4 / 256)           // 2048
#define CONV_W_BLOCKS ((DTOT * DMODEL / 4) / 256)         // 5312
__global__ __launch_bounds__(256) void conv_uw(const float* __restrict__ usrc,
        const float* __restrict__ wsrc, u16* __restrict__ u_hi,
        u16* __restrict__ u_lo, u16* __restrict__ w_hi, u16* __restrict__ w_lo) {
    const int bid = blockIdx.x;
    if (bid < CONV_U_BLOCKS) {
        const size_t i4 = ((size_t)bid * 256 + threadIdx.x) * 4;
        const float4 v = *(const float4*)(usrc + i4);
        const unsigned int h0 = f2bf(v.x), h1 = f2bf(v.y), h2 = f2bf(v.z), h3 = f2bf(v.w);
        uint2 hw, lw;
        hw.x = h0 | (h1 << 16); hw.y = h2 | (h3 << 16);
        lw.x = pk(v.x - __uint_as_float(h0 << 16), v.y - __uint_as_float(h1 << 16));
        lw.y = pk(v.z - __uint_as_float(h2 << 16), v.w - __uint_as_float(h3 << 16));
        *(uint2*)(u_hi + i4) = hw;
        *(uint2*)(u_lo + i4) = lw;
    } else {
        const size_t i4 = ((size_t)(bid - CONV_U_BLOCKS) * 256 + threadIdx.x) * 4;
        const float4 v = *(const float4*)(wsrc + i4);
        const unsigned int h0 = f2bf(v.x), h1 = f2bf(v.y), h2 = f2bf(v.z), h3 = f2bf(v.w);
        uint2 hw, lw;
        hw.x = h0 | (h1 << 16); hw.y = h2 | (h3 << 16);
        lw.x = pk(v.x - __uint_as_float(h0 << 16), v.y - __uint_as_float(h1 << 16));
        lw.y = pk(v.z - __uint_as_float(h2 << 16), v.w - __uint_as_float(h3 << 16));
        *(uint2*)(w_hi + i4) = hw;
        if ((i4 >> 10) >= NZX)
            *(uint2*)(w_lo + (i4 - (size_t)NZX * DMODEL)) = lw;
    }
}

// ---------------------------------------------------------------------------
// merged in_proj GEMM, longest-job-first order: blocks 0..303 = rem3 (slow,
// 32 K-iters), 304..815 = z/x (fast, 16 K-iters). With 512 concurrent slots
// (2 blk/CU), long rem3 blocks start in round 1 and short zx blocks backfill
// -> removes the 59%-full second round of the old order. 304 % 8 == 0, so
// the zx XCD remap (bid&7 == hardware XCD) is preserved. zx loop reverted to
// the proven __syncthreads 2-phase (r23: 49.1us vs r24 counted-vmcnt 50.9).
// ---------------------------------------------------------------------------
#define ZX_BLOCKS 512
#define R3_BLOCKS ((NREM / 64) * (ROWS / 128))   // 19*16 = 304
__global__ __launch_bounds__(256) void mfma_inproj(const u16* __restrict__ u_bf,
        const u16* __restrict__ u_lo, const u16* __restrict__ w_bf,
        const u16* __restrict__ w_lo, float* __restrict__ zx) {
    __shared__ u16 smem[32768];    // 64 KB union
    const int tid = threadIdx.x;
    const int lane = tid & 63, wave = tid >> 6;
    const int wr = wave >> 1, wc = wave & 1;
    const int lr = lane >> 4, lc = lane & 15;

    if (blockIdx.x >= R3_BLOCKS) {
        // ---------------- z/x branch (BK=64, XCD remap, 2-phase) ----------
        const int bid = blockIdx.x - R3_BLOCKS;     // 0..511; bid&7 == XCD
        const int kx = bid & 7, lx = bid >> 3;
        const int mt = (kx >> 2) * 8 + (lx >> 3);   // 0..15
        const int nt = (kx & 3) * 8 + (lx & 7);     // 0..31
        const int m0 = mt * 128, n0 = nt * 128;
        const int sr = tid >> 3;
        const int sc = (((tid & 7) ^ ((tid >> 4) & 7)) * 8);
        f32x4 acc[4][4] = {};
        const u16* pA = u_bf + (size_t)(m0 + sr) * DMODEL + sc;
        const u16* pB = w_bf + (size_t)(n0 + sr) * DMODEL + sc;
        u16* Al = smem;              // buf stride 8192 u16
        u16* Bl = smem + 16384;

#define STAGE_ZX(buf, k0) {                                                       \
        gload16(pA + (k0),                       Al + (buf)*8192 + tid*8);        \
        gload16(pA + (k0) + (size_t)32 * DMODEL, Al + (buf)*8192 + tid*8 + 2048); \
        gload16(pA + (k0) + (size_t)64 * DMODEL, Al + (buf)*8192 + tid*8 + 4096); \
        gload16(pA + (k0) + (size_t)96 * DMODEL, Al + (buf)*8192 + tid*8 + 6144); \
        gload16(pB + (k0),                       Bl + (buf)*8192 + tid*8);        \
        gload16(pB + (k0) + (size_t)32 * DMODEL, Bl + (buf)*8192 + tid*8 + 2048); \
        gload16(pB + (k0) + (size_t)64 * DMODEL, Bl + (buf)*8192 + tid*8 + 4096); \
        gload16(pB + (k0) + (size_t)96 * DMODEL, Bl + (buf)*8192 + tid*8 + 6144); }

        STAGE_ZX(0, 0);
        __syncthreads();
        int cur = 0;
        for (int k0 = 0; k0 < DMODEL; k0 += 64) {
            if (k0 + 64 < DMODEL) STAGE_ZX(cur ^ 1, k0 + 64);
            #pragma unroll
            for (int kk = 0; kk < 2; ++kk) {
                s16x8 af[4], bf[4];
                #pragma unroll
                for (int f = 0; f < 4; ++f) {
                    const int ra = wr * 64 + f * 16 + lc;
                    af[f] = *(const s16x8*)&Al[cur * 8192 + ra * 64 + (((kk * 4 + lr) ^ SWZ8(ra)) * 8)];
                    const int rb = wc * 64 + f * 16 + lc;
                    bf[f] = *(const s16x8*)&Bl[cur * 8192 + rb * 64 + (((kk * 4 + lr) ^ SWZ8(rb)) * 8)];
                }
                #pragma unroll
                for (int fm = 0; fm < 4; ++fm)
                    #pragma unroll
                    for (int fn = 0; fn < 4; ++fn)
                        acc[fm][fn] = __builtin_amdgcn_mfma_f32_16x16x32_bf16(
                            af[fm], bf[fn], acc[fm][fn], 0, 0, 0);
            }
            __syncthreads();
            cur ^= 1;
        }
#undef STAGE_ZX

        #pragma unroll
        for (int fm = 0; fm < 4; ++fm)
            #pragma unroll
            for (int fn = 0; fn < 4; ++fn) {
                const size_t col = n0 + wc * 64 + fn * 16 + lc;
                #pragma unroll
                for (int j = 0; j < 4; ++j) {
                    const size_t row = m0 + wr * 64 + fm * 16 + lr * 4 + j;
                    zx[row * DTOT + col] = acc[fm][fn][j];
                }
            }
    } else {
        // ---------------- rem3 branch (BK=32, 3-pass split; first) --------
        const int rid = blockIdx.x;
        const int m0 = (rid / (NREM / 64)) * 128, n0 = (rid % (NREM / 64)) * 64;
        const int sr = tid >> 2;
        const int sc = (((tid & 3) ^ SWZ(tid >> 2)) * 8);
        f32x4 acc[4][2] = {};
        const u16* pAh = u_bf + (size_t)(m0 + sr) * DMODEL + sc;
        const u16* pAl = u_lo + (size_t)(m0 + sr) * DMODEL + sc;
        const u16* pBh = w_bf + (size_t)(NZX + n0 + sr) * DMODEL + sc;
        const u16* pBl = w_lo + (size_t)(n0 + sr) * DMODEL + sc;
        u16* Ah  = smem;             // buf stride 4096 u16
        u16* Alo = smem + 8192;
        u16* Bh  = smem + 16384;     // buf stride 2048 u16
        u16* Blo = smem + 20480;

#define STAGE_R3(buf, k0) {                                                          \
        gload16(pAh + (k0),                       Ah  + (buf)*4096 + tid*8);         \
        gload16(pAh + (k0) + (size_t)64 * DMODEL, Ah  + (buf)*4096 + tid*8 + 2048);  \
        gload16(pAl + (k0),                       Alo + (buf)*4096 + tid*8);         \
        gload16(pAl + (k0) + (size_t)64 * DMODEL, Alo + (buf)*4096 + tid*8 + 2048);  \
        gload16(pBh + (k0),                       Bh  + (buf)*2048 + tid*8);         \
        gload16(pBl + (k0),                       Blo + (buf)*2048 + tid*8); }

        STAGE_R3(0, 0);
        __syncthreads();
        int cur = 0;
        for (int k0 = 0; k0 < DMODEL; k0 += 32) {
            if (k0 + 32 < DMODEL) STAGE_R3(cur ^ 1, k0 + 32);
            s16x8 ahf[4], alf[4], bhf[2], blf[2];
            #pragma unroll
            for (int f = 0; f < 4; ++f) {
                const int ra = wr * 64 + f * 16 + lc;
                const int oa = ra * 32 + ((lr ^ SWZ(ra)) * 8);
                ahf[f] = *(const s16x8*)&Ah[cur * 4096 + oa];
                alf[f] = *(const s16x8*)&Alo[cur * 4096 + oa];
            }
            #pragma unroll
            for (int f = 0; f < 2; ++f) {
                const int rb = wc * 32 + f * 16 + lc;
                const int ob = rb * 32 + ((lr ^ SWZ(rb)) * 8);
                bhf[f] = *(const s16x8*)&Bh[cur * 2048 + ob];
                blf[f] = *(const s16x8*)&Blo[cur * 2048 + ob];
            }
            #pragma unroll
            for (int fm = 0; fm < 4; ++fm)
                #pragma unroll
                for (int fn = 0; fn < 2; ++fn) {
                    acc[fm][fn] = __builtin_amdgcn_mfma_f32_16x16x32_bf16(
                        ahf[fm], bhf[fn], acc[fm][fn], 0, 0, 0);
                    acc[fm][fn] = __builtin_amdgcn_mfma_f32_16x16x32_bf16(
                        ahf[fm], blf[fn], acc[fm][fn], 0, 0, 0);
                    acc[fm][fn] = __builtin_amdgcn_mfma_f32_16x16x32_bf16(
                        alf[fm], bhf[fn], acc[fm][fn], 0, 0, 0);
                }
            __syncthreads();
            cur ^= 1;
        }
#undef STAGE_R3

        #pragma unroll
        for (int fm = 0; fm < 4; ++fm)
            #pragma unroll
            for (int fn = 0; fn < 2; ++fn) {
                const size_t col = NZX + n0 + wc * 32 + fn * 16 + lc;
                #pragma unroll
                for (int j = 0; j < 4; ++j) {
                    const size_t row = m0 + wr * 64 + fm * 16 + lr * 4 + j;
                    zx[row * DTOT + col] = acc[fm][fn][j];
                }
            }
    }
}

// ---------------------------------------------------------------------------
// bf16 MFMA GEMM, 128x64 tile, BK=64: out = gn_bf @ wo_bf^T (LDS 48KB)
// ---------------------------------------------------------------------------
__global__ __launch_bounds__(256) void mfma_gemm_out(const u16* __restrict__ A,
                                                     const u16* __restrict__ B,
                                                     float* __restrict__ C,
                                                     int K, int ldc) {
    __shared__ u16 Als[2][128 * 64];
    __shared__ u16 Bls[2][64 * 64];
    const int tid = threadIdx.x;
    const int m0 = blockIdx.y * 128, n0 = blockIdx.x * 64;
    const int lane = tid & 63, wave = tid >> 6;
    const int wr = wave >> 1, wc = wave & 1;
    const int lr = lane >> 4, lc = lane & 15;
    const int sr = tid >> 3;
    const int sc = (((tid & 7) ^ ((tid >> 4) & 7)) * 8);

    f32x4 acc[4][2] = {};

    const u16* pA = A + (size_t)(m0 + sr) * K + sc;
    const u16* pB = B + (size_t)(n0 + sr) * K + sc;

#define STAGE_OUT(buf, k0) {                                                  \
        gload16(pA + (k0),                   &Als[buf][tid * 8]);             \
        gload16(pA + (k0) + (size_t)32 * K,  &Als[buf][tid * 8 + 2048]);      \
        gload16(pA + (k0) + (size_t)64 * K,  &Als[buf][tid * 8 + 4096]);      \
        gload16(pA + (k0) + (size_t)96 * K,  &Als[buf][tid * 8 + 6144]);      \
        gload16(pB + (k0),                   &Bls[buf][tid * 8]);             \
        gload16(pB + (k0) + (size_t)32 * K,  &Bls[buf][tid * 8 + 2048]); }

    STAGE_OUT(0, 0);
    __syncthreads();
    int cur = 0;
    for (int k0 = 0; k0 < K; k0 += 64) {
        if (k0 + 64 < K) STAGE_OUT(cur ^ 1, k0 + 64);
        #pragma unroll
        for (int kk = 0; kk < 2; ++kk) {
            s16x8 af[4], bf[2];
            #pragma unroll
            for (int f = 0; f < 4; ++f) {
                const int ra = wr * 64 + f * 16 + lc;
                af[f] = *(const s16x8*)&Als[cur][ra * 64 + (((kk * 4 + lr) ^ SWZ8(ra)) * 8)];
            }
            #pragma unroll
            for (int f = 0; f < 2; ++f) {
                const int rb = wc * 32 + f * 16 + lc;
                bf[f] = *(const s16x8*)&Bls[cur][rb * 64 + (((kk * 4 + lr) ^ SWZ8(rb)) * 8)];
            }
            #pragma unroll
            for (int fm = 0; fm < 4; ++fm)
                #pragma unroll
                for (int fn = 0; fn < 2; ++fn)
                    acc[fm][fn] = __builtin_amdgcn_mfma_f32_16x16x32_bf16(
                        af[fm], bf[fn], acc[fm][fn], 0, 0, 0);
        }
        __syncthreads();
        cur ^= 1;
    }
#undef STAGE_OUT

    #pragma unroll
    for (int fm = 0; fm < 4; ++fm)
        #pragma unroll
        for (int fn = 0; fn < 2; ++fn) {
            const size_t col = n0 + wc * 32 + fn * 16 + lc;
            #pragma unroll
            for (int j = 0; j < 4; ++j) {
                const size_t row = m0 + wr * 64 + fm * 16 + lr * 4 + j;
                C[row * (size_t)ldc + col] = acc[fm][fn][j];
            }
        }
}

// ---------------------------------------------------------------------------
// merged prep + cumsum (both only READ zx; outputs disjoint -> race-free).
// ---------------------------------------------------------------------------
__global__ __launch_bounds__(256) void prep_cumsum(const float* __restrict__ zx,
        const float* __restrict__ dt_bias, const float* __restrict__ A_log,
        const float* __restrict__ B_norm_w, const float* __restrict__ C_norm_w,
        float* __restrict__ Bg, float* __restrict__ Cg,
        float4* __restrict__ abg4, float* __restrict__ th_cs) {
    __shared__ float sums[8][33];
    const int bid = blockIdx.x;
    const int tid = threadIdx.x;
    if (bid < 512) {
        const int bl = bid * 4 + (tid >> 6);
        const int t  = tid & 63;
        const int b = bl >> 10, l = bl & (LSEQ - 1);
        const float* row = zx + (size_t)bl * DTOT;
        const float br = row[OFF_BR + t];
        const float cr = row[OFF_CR + t];
        float ssb = br * br, ssc = cr * cr;
        #pragma unroll
        for (int k = 1; k < 64; k <<= 1) { ssb += __shfl_xor(ssb, k); ssc += __shfl_xor(ssc, k); }
        const float scB = rsqrtf(ssb * (1.f / 64.f) + 1e-5f);
        const float scC = rsqrtf(ssc * (1.f / 64.f) + 1e-5f);
        Bg[(size_t)bl * 64 + t] = br * scB * B_norm_w[t];
        Cg[(size_t)bl * 64 + t] = cr * scC * C_norm_w[t];
        if (t < NH) {
            const float dtr = row[OFF_DT + t] + dt_bias[t];
            const float dt  = (dtr > 20.f) ? dtr : log1pf(expf(dtr));
            const float lamr = row[OFF_LAM + t];
            const float lam  = 1.f / (1.f + expf(-lamr));
            const float Ah   = -expf(A_log[t]);
            const float al   = expf(dt * Ah);
            const float bp   = (1.f - lam) * dt;        // beta' = b/a
            const size_t o = ((size_t)b * NH + t) * LSEQ + l;
            abg4[o] = make_float4(al, bp * al, lam * dt, bp);
        }
    } else {
        const int bh = bid - 512;
        const int b = bh >> 5, h = bh & 31;
        const int d = tid & 31, seg = tid >> 5;
        const float* base = zx + (size_t)b * LSEQ * DTOT + OFF_TH + h * 32 + d;
        float* out = th_cs + (size_t)b * LSEQ * 1024 + h * 32 + d;
        const int l0 = seg * 128;
        float s = 0.f;
        #pragma unroll 4
        for (int i = 0; i < 128; ++i) s += base[(size_t)(l0 + i) * DTOT];
        sums[seg][d] = s;
        __syncthreads();
        float acc = 0.f;
        for (int s2 = 0; s2 < seg; ++s2) acc += sums[s2][d];
        #pragma unroll 4
        for (int i = 0; i < 128; ++i) {
            acc += base[(size_t)(l0 + i) * DTOT];
            out[(size_t)(l0 + i) * 1024] = acc;
        }
    }
}

// ---------------------------------------------------------------------------
// rot: Bh/Ch = rot(broadcast(Bg/Cg)+bias). Brot/Crot layout (B,NH,L,DS).
// ---------------------------------------------------------------------------
__global__ __launch_bounds__(256) void rot_kernel(const float* __restrict__ th_cs,
        const float* __restrict__ Bg, const float* __restrict__ Cg,
        const float* __restrict__ B_bias, const float* __restrict__ C_bias,
        float* __restrict__ Brot, float* __restrict__ Crot) {
    const size_t idx = (size_t)blockIdx.x * 256 + threadIdx.x;
    const int j = (int)(idx & 31);
    const int h = (int)((idx >> 5) & 31);
    const size_t bl = idx >> 10;
    const int l = (int)(bl & (LSEQ - 1));
    const int b = (int)(bl >> 10);
    const float th = th_cs[idx];
    float s, c;
    sincosf(th, &s, &c);
    float v1 = Bg[bl * 64 + j]      + B_bias[h * 64 + j];
    float v2 = Bg[bl * 64 + 32 + j] + B_bias[h * 64 + 32 + j];
    const size_t ob = ((size_t)(b * NH + h) * LSEQ + l) * DS + j;
    Brot[ob]      = v1 * c - v2 * s;
    Brot[ob + 32] = v1 * s + v2 * c;
    v1 = Cg[bl * 64 + j]      + C_bias[h * 64 + j];
    v2 = Cg[bl * 64 + 32 + j] + C_bias[h * 64 + 32 + j];
    Crot[ob]      = v1 * c - v2 * s;
    Crot[ob + 32] = v1 * s + v2 * c;
}

// ---------------------------------------------------------------------------
// wcalc: per (b,h,seg): within-seg log-cumsum of alpha; emits
//   wbuf[t], Lbuf[t], aprod[s], bscale[s]  (round 13/15 derivation)
// ---------------------------------------------------------------------------
__global__ __launch_bounds__(64) void wcalc_kernel(const float4* __restrict__ abg4,
        float* __restrict__ wbuf, float* __restrict__ aprod,
        float* __restrict__ bscale, float* __restrict__ Lbuf) {
    const int bh = blockIdx.x;
    const int lane = threadIdx.x;
    const int seg = lane >> 3, sub = lane & 7;
    const int t0 = seg * SEG;
    const int sbase = t0 + sub * 16;
    const float4* ab = abg4 + (size_t)bh * LSEQ;

    float part = 0.f;
    #pragma unroll
    for (int i = 0; i < 16; ++i) part += logf(ab[sbase + i].x);
    float incl = part;
    #pragma unroll
    for (int d = 1; d < 8; d <<= 1) {
        const float v = __shfl_up(incl, d, 8);
        if (sub >= d) incl += v;
    }
    const float LE = __shfl(incl, 7, 8);
    float Lrun = incl - part;                // exclusive prefix

    for (int i = 0; i < 16; ++i) {
        const int s = sbase + i;
        const float4 A = ab[s];
        Lrun += logf(A.x);
        Lbuf[(size_t)bh * LSEQ + s] = Lrun;
        float w;
        if ((s & (SEG - 1)) == (SEG - 1)) w = A.z;
        else w = __expf(LE - Lrun) * (A.z + ab[s + 1].w);
        wbuf[(size_t)bh * LSEQ + s] = w;
    }
    if (sub == 0) {
        aprod[bh * NSEG + seg] = __expf(LE);
        bscale[bh * NSEG + seg] = (seg > 0) ? __expf(LE) * ab[t0].w : 0.f;
    }
}

// ---------------------------------------------------------------------------
// hseg_gemm: h_local_end[p,n] = sum_s wbuf_s * x_s[p] * B_s[n] (split-bf16 3-pass)
// ---------------------------------------------------------------------------
#define WK 136
__global__ __launch_bounds__(256) void hseg_gemm(const float* __restrict__ zx,
        const float* __restrict__ Brot, const float* __restrict__ wbuf,
        float* __restrict__ hseg) {
    __shared__ u16 XH[64][WK], XL[64][WK], BHs[64][WK], BLs[64][WK];
    const int blk = blockIdx.x;
    const int seg = blk & (NSEG - 1), bh = blk >> 3;
    const int b = bh >> 5, h = bh & 31;
    const int tid = threadIdx.x;

    {
        const int sIdx = tid >> 1, half = tid & 1;
        const int t = seg * SEG + sIdx;
        const float wv = wbuf[(size_t)bh * LSEQ + t];
        const float* xsrc = zx + ((size_t)b * LSEQ + t) * DTOT + OFF_X + h * 64 + half * 32;
        const float* bsrc = Brot + ((size_t)bh * LSEQ + t) * DS + half * 32;
        #pragma unroll
        for (int i = 0; i < 32; i += 4) {
            const float4 xv = *(const float4*)(xsrc + i);
            const float4 bv = *(const float4*)(bsrc + i);
            const int p0 = half * 32 + i;
            u16 hi, lo;
            split1(xv.x * wv, hi, lo); XH[p0 + 0][sIdx] = hi; XL[p0 + 0][sIdx] = lo;
            split1(xv.y * wv, hi, lo); XH[p0 + 1][sIdx] = hi; XL[p0 + 1][sIdx] = lo;
            split1(xv.z * wv, hi, lo); XH[p0 + 2][sIdx] = hi; XL[p0 + 2][sIdx] = lo;
            split1(xv.w * wv, hi, lo); XH[p0 + 3][sIdx] = hi; XL[p0 + 3][sIdx] = lo;
            split1(bv.x, hi, lo); BHs[p0 + 0][sIdx] = hi; BLs[p0 + 0][sIdx] = lo;
            split1(bv.y, hi, lo); BHs[p0 + 1][sIdx] = hi; BLs[p0 + 1][sIdx] = lo;
            split1(bv.z, hi, lo); BHs[p0 + 2][sIdx] = hi; BLs[p0 + 2][sIdx] = lo;
            split1(bv.w, hi, lo); BHs[p0 + 3][sIdx] = hi; BLs[p0 + 3][sIdx] = lo;
        }
    }
    __syncthreads();

    const int lane = tid & 63, wave = tid >> 6;
    const int wR = wave >> 1, wC = wave & 1;
    const int lr = lane >> 4, lc = lane & 15;

    f32x4 acc[2][2] = {};
    #pragma unroll
    for (int ks = 0; ks < 4; ++ks) {
        const int k0 = ks * 32;
        s16x8 xh[2], xl[2], bhf[2], blf[2];
        #pragma unroll
        for (int f = 0; f < 2; ++f) {
            const int pr = wR * 32 + f * 16 + lc;
            xh[f] = *(const s16x8*)&XH[pr][k0 + lr * 8];
            xl[f] = *(const s16x8*)&XL[pr][k0 + lr * 8];
            const int nr = wC * 32 + f * 16 + lc;
            bhf[f] = *(const s16x8*)&BHs[nr][k0 + lr * 8];
            blf[f] = *(const s16x8*)&BLs[nr][k0 + lr * 8];
        }
        #pragma unroll
        for (int fm = 0; fm < 2; ++fm)
            #pragma unroll
            for (int fn = 0; fn < 2; ++fn) {
                acc[fm][fn] = __builtin_amdgcn_mfma_f32_16x16x32_bf16(
                    xh[fm], bhf[fn], acc[fm][fn], 0, 0, 0);
                acc[fm][fn] = __builtin_amdgcn_mfma_f32_16x16x32_bf16(
                    xh[fm], blf[fn], acc[fm][fn], 0, 0, 0);
                acc[fm][fn] = __builtin_amdgcn_mfma_f32_16x16x32_bf16(
                    xl[fm], bhf[fn], acc[fm][fn], 0, 0, 0);
            }
    }

    float* hp = hseg + ((size_t)(bh * NSEG + seg) * HD) * DS;
    #pragma unroll
    for (int fm = 0; fm < 2; ++fm)
        #pragma unroll
        for (int fn = 0; fn < 2; ++fn) {
            const int n = wC * 32 + fn * 16 + lc;
            #pragma unroll
            for (int j = 0; j < 4; ++j) {
                const int p = wR * 32 + fm * 16 + lr * 4 + j;
                hp[p * DS + n] = acc[fm][fn][j];
            }
        }
}

// ---------------------------------------------------------------------------
// scan_fix: sequential over segments -> hseg becomes hstar per segment.
// ---------------------------------------------------------------------------
__global__ __launch_bounds__(256) void scan_fix(float* __restrict__ hseg,
        const float* __restrict__ aprod, const float* __restrict__ bscale,
        const float* __restrict__ zx, const float* __restrict__ Brot,
        const float4* __restrict__ abg4) {
    const int blk = blockIdx.x;          // (b,h,ptile): 256
    const int ptile = blk & 3, h = (blk >> 2) & 31, b = blk >> 7;
    const int tid = threadIdx.x;
    const int pl = tid >> 4, ng = tid & 15;
    const int p = ptile * 16 + pl;
    const int n0 = ng * 4;
    const size_t bh = (size_t)b * NH + h;

    float4 cur = make_float4(0.f, 0.f, 0.f, 0.f);
    #pragma unroll
    for (int s = 0; s < NSEG; ++s) {
        float* hp = hseg + (((bh * NSEG + s) * HD + p) * DS + n0);
        float4 tmp = *(const float4*)hp;     // local h_end (no boundary)
        float4 hst = cur;                    // hstar = h_start (+ r1 below)
        if (s > 0) {
            const float bs = bscale[bh * NSEG + s];          // aprod*beta'
            const float bp0 = abg4[bh * LSEQ + s * SEG].w;   // beta'_{t0}
            const int tm1 = s * SEG - 1;
            const float4 Bm = *(const float4*)(Brot + ((size_t)bh * LSEQ + tm1) * DS + n0);
            const float xm = zx[((size_t)b * LSEQ + tm1) * DTOT + OFF_X + h * HD + p];
            const float fb = bs * xm;
            const float f1 = bp0 * xm;
            tmp.x = fmaf(fb, Bm.x, tmp.x);
            tmp.y = fmaf(fb, Bm.y, tmp.y);
            tmp.z = fmaf(fb, Bm.z, tmp.z);
            tmp.w = fmaf(fb, Bm.w, tmp.w);
            hst.x = fmaf(f1, Bm.x, hst.x);
            hst.y = fmaf(f1, Bm.y, hst.y);
            hst.z = fmaf(f1, Bm.z, hst.z);
            hst.w = fmaf(f1, Bm.w, hst.w);
        }
        *(float4*)hp = hst;
        const float a = aprod[bh * NSEG + s];
        cur.x = fmaf(a, cur.x, tmp.x);
        cur.y = fmaf(a, cur.y, tmp.y);
        cur.z = fmaf(a, cur.z, tmp.z);
        cur.w = fmaf(a, cur.w, tmp.w);
    }
}

// ---------------------------------------------------------------------------
// ssd_y v3: C/B/H fragments from global (L2); Gw fp32 in LDS with D folded
// into the diagonal; X^T staged in LDS in two 64-step halves. 2 blocks/CU.
// ---------------------------------------------------------------------------
#define GWF 132
#define XTS 72
__global__ __launch_bounds__(256, 2) void ssd_y(const float* __restrict__ zx,
        const float* __restrict__ Brot, const float* __restrict__ Crot,
        const float4* __restrict__ abg4, const float* __restrict__ hseg,
        const float* __restrict__ Lbuf, const float* __restrict__ Dp,
        float* __restrict__ yb) {
    __shared__ float Gw[128 * GWF];
    __shared__ u16 XTh[64 * XTS];
    __shared__ float Ls[128], gbs[128], gms[128], eLs[128];

    const int blk = blockIdx.x;
    const int seg = blk & (NSEG - 1), bh = blk >> 3;
    const int b = bh >> 5, h = bh & 31;
    const int tid = threadIdx.x;
    const int t0 = seg * SEG;
    const int lane = tid & 63, wave = tid >> 6;
    const int wr = wave >> 1, wc = wave & 1;
    const int lr = lane >> 4, lc = lane & 15;

    if (tid < 128) {
        const int t = t0 + tid;
        const float4 A = abg4[(size_t)bh * LSEQ + t];
        const float Lv = Lbuf[(size_t)bh * LSEQ + t];
        Ls[tid] = Lv;
        gms[tid] = A.z;
        gbs[tid] = (tid < 127) ? A.z + abg4[(size_t)bh * LSEQ + t + 1].w : 0.f;
        eLs[tid] = __expf(Lv);
    }
    __syncthreads();

    const float* Cbase = Crot + ((size_t)bh * LSEQ + t0) * DS;
    const float* Bbase = Brot + ((size_t)bh * LSEQ + t0) * DS;
    const float* Hbase = hseg + ((size_t)(bh * NSEG + seg) * HD) * DS;
    const float* Xbase = zx + ((size_t)b * LSEQ + t0) * DTOT + OFF_X + h * 64;

    f32x4 accP[4][2] = {};
    f32x4 accG[4][4] = {};
    #pragma unroll
    for (int ks = 0; ks < 2; ++ks) {
        const int k0 = ks * 32 + lr * 8;
        s16x8 ch[4], cl4[4], bh4[4], bl4[4], hh2[2];
        #pragma unroll
        for (int f = 0; f < 4; ++f) {
            const int rowc = wr * 64 + f * 16 + lc;
            const float4 c0 = *(const float4*)(Cbase + (size_t)rowc * DS + k0);
            const float4 c1 = *(const float4*)(Cbase + (size_t)rowc * DS + k0 + 4);
            split8(c0, c1, ch[f], cl4[f]);
            const int rowb = wc * 64 + f * 16 + lc;
            const float4 b0 = *(const float4*)(Bbase + (size_t)rowb * DS + k0);
            const float4 b1 = *(const float4*)(Bbase + (size_t)rowb * DS + k0 + 4);
            split8(b0, b1, bh4[f], bl4[f]);
        }
        #pragma unroll
        for (int f = 0; f < 2; ++f) {
            const int rowp = wc * 32 + f * 16 + lc;
            const float4 h0 = *(const float4*)(Hbase + (size_t)rowp * DS + k0);
            const float4 h1 = *(const float4*)(Hbase + (size_t)rowp * DS + k0 + 4);
            cvt8(h0, h1, hh2[f]);
        }
        #pragma unroll
        for (int fm = 0; fm < 4; ++fm) {
            #pragma unroll
            for (int fn = 0; fn < 4; ++fn) {
                accG[fm][fn] = __builtin_amdgcn_mfma_f32_16x16x32_bf16(
                    ch[fm], bh4[fn], accG[fm][fn], 0, 0, 0);
                accG[fm][fn] = __builtin_amdgcn_mfma_f32_16x16x32_bf16(
                    ch[fm], bl4[fn], accG[fm][fn], 0, 0, 0);
                accG[fm][fn] = __builtin_amdgcn_mfma_f32_16x16x32_bf16(
                    cl4[fm], bh4[fn], accG[fm][fn], 0, 0, 0);
            }
            #pragma unroll
            for (int fn = 0; fn < 2; ++fn) {
                accP[fm][fn] = __builtin_amdgcn_mfma_f32_16x16x32_bf16(
                    ch[fm], hh2[fn], accP[fm][fn], 0, 0, 0);
                accP[fm][fn] = __builtin_amdgcn_mfma_f32_16x16x32_bf16(
                    cl4[fm], hh2[fn], accP[fm][fn], 0, 0, 0);
            }
        }
    }

    const float Dh = Dp[h];
    #pragma unroll
    for (int fm = 0; fm < 4; ++fm)
        #pragma unroll
        for (int fn = 0; fn < 4; ++fn)
            #pragma unroll
            for (int jj = 0; jj < 4; ++jj) {
                const int i = wr * 64 + fm * 16 + lr * 4 + jj;
                const int j = wc * 64 + fn * 16 + lc;
                float v;
                if (j < i)       v = accG[fm][fn][jj] * __expf(Ls[i] - Ls[j]) * gbs[j];
                else if (j == i) v = accG[fm][fn][jj] * gms[i] + Dh;
                else             v = 0.f;
                Gw[i * GWF + j] = v;
            }

    f32x4 accY[4][2];
    #pragma unroll
    for (int fm = 0; fm < 4; ++fm)
        #pragma unroll
        for (int fn = 0; fn < 2; ++fn)
            #pragma unroll
            for (int jj = 0; jj < 4; ++jj) {
                const int i = wr * 64 + fm * 16 + lr * 4 + jj;
                accY[fm][fn][jj] = eLs[i] * accP[fm][fn][jj];
            }

#define STAGE_XT(H) {                                                        \
        const int lp = tid >> 2, pq = (tid & 3) * 16;                        \
        const float* xs = Xbase + (size_t)((H) * 64 + lp) * DTOT + pq;       \
        _Pragma("unroll")                                                    \
        for (int i = 0; i < 16; i += 4) {                                    \
            const float4 xv = *(const float4*)(xs + i);                      \
            XTh[(pq + i + 0) * XTS + lp] = (u16)f2bf(xv.x);                  \
            XTh[(pq + i + 1) * XTS + lp] = (u16)f2bf(xv.y);                  \
            XTh[(pq + i + 2) * XTS + lp] = (u16)f2bf(xv.z);                  \
            XTh[(pq + i + 3) * XTS + lp] = (u16)f2bf(xv.w);                  \
        }                                                                    \
    }
    STAGE_XT(0);
    __syncthreads();

    #pragma unroll
    for (int ks = 0; ks < 4; ++ks) {
        if (ks == 2) {
            __syncthreads();
            STAGE_XT(1);
            __syncthreads();
        }
        const int k0 = ks * 32 + lr * 8;
        const int kl = (ks & 1) * 32 + lr * 8;
        s16x8 gh4[4], gl4[4], xf[2];
        #pragma unroll
        for (int f = 0; f < 4; ++f) {
            const int rowi = wr * 64 + f * 16 + lc;
            const float4 g0 = *(const float4*)&Gw[rowi * GWF + k0];
            const float4 g1 = *(const float4*)&Gw[rowi * GWF + k0 + 4];
            split8(g0, g1, gh4[f], gl4[f]);
        }
        #pragma unroll
        for (int f = 0; f < 2; ++f) {
            const int rowp = wc * 32 + f * 16 + lc;
            xf[f] = *(const s16x8*)&XTh[rowp * XTS + kl];
        }
        #pragma unroll
        for (int fm = 0; fm < 4; ++fm)
            #pragma unroll
            for (int fn = 0; fn < 2; ++fn) {
                accY[fm][fn] = __builtin_amdgcn_mfma_f32_16x16x32_bf16(
                    gh4[fm], xf[fn], accY[fm][fn], 0, 0, 0);
                accY[fm][fn] = __builtin_amdgcn_mfma_f32_16x16x32_bf16(
                    gl4[fm], xf[fn], accY[fm][fn], 0, 0, 0);
            }
    }
#undef STAGE_XT

    #pragma unroll
    for (int fm = 0; fm < 4; ++fm)
        #pragma unroll
        for (int fn = 0; fn < 2; ++fn) {
            const int p = wc * 32 + fn * 16 + lc;
            #pragma unroll
            for (int jj = 0; jj < 4; ++jj) {
                const int i = wr * 64 + fm * 16 + lr * 4 + jj;
                yb[((size_t)b * LSEQ + t0 + i) * DIN + h * 64 + p] = accY[fm][fn][jj];
            }
        }
}

// ---------------------------------------------------------------------------
// merged gate+RMS-norm (blocks 0..2047) and out_proj_w conversion (rest).
// ---------------------------------------------------------------------------
__global__ __launch_bounds__(256) void gate_convwo(const float* __restrict__ yb,
        const float* __restrict__ zx, const float* __restrict__ norm_w,
        u16* __restrict__ gnb, const float* __restrict__ wo_src,
        u16* __restrict__ wo_hi) {
    if (blockIdx.x < ROWS) {
        const int bl = blockIdx.x;
        const int tid = threadIdx.x;
        const float* yrow = yb + (size_t)bl * DIN;
        const float* zrow = zx + (size_t)bl * DTOT + OFF_Z;
        float g[8];
        float ss = 0.f;
        #pragma unroll
        for (int i = 0; i < 8; ++i) {
            const int c = tid + i * 256;
            const float yv = yrow[c];
            const float zv = zrow[c];
            const float sg = 1.f / (1.f + expf(-zv));
            const float gv = yv * zv * sg;
            g[i] = gv;
            ss += gv * gv;
        }
        #pragma unroll
        for (int k = 1; k < 64; k <<= 1) ss += __shfl_xor(ss, k);
        __shared__ float wsum[4];
        if ((tid & 63) == 0) wsum[tid >> 6] = ss;
        __syncthreads();
        ss = wsum[0] + wsum[1] + wsum[2] + wsum[3];
        const float sc = rsqrtf(ss * (1.f / 2048.f) + 1e-5f);
        #pragma unroll
        for (int i = 0; i < 8; ++i) {
            const int c = tid + i * 256;
            gnb[(size_t)bl * DIN + c] = (u16)f2bf(g[i] * sc * norm_w[c]);
        }
    } else {
        const size_t i4 = ((size_t)(blockIdx.x - ROWS) * 256 + threadIdx.x) * 4;
        const float4 v = *(const float4*)(wo_src + i4);
        uint2 hw;
        hw.x = pk(v.x, v.y); hw.y = pk(v.z, v.w);
        *(uint2*)(wo_hi + i4) = hw;
    }
}

// ---------------------------------------------------------------------------
extern "C" void kernel_launch(void* const* d_in, const int* in_sizes, int n_in,
                              void* d_out, int out_size, void* d_ws, size_t ws_size,
                              hipStream_t stream) {
    const float* u          = (const float*)d_in[0];
    const float* in_proj_w  = (const float*)d_in[1];
    const float* dt_bias    = (const float*)d_in[2];
    const float* A_log      = (const float*)d_in[3];
    const float* Dp         = (const float*)d_in[4];
    const float* B_norm_w   = (const float*)d_in[5];
    const float* C_norm_w   = (const float*)d_in[6];
    const float* B_bias     = (const float*)d_in[7];
    const float* C_bias     = (const float*)d_in[8];
    const float* norm_w     = (const float*)d_in[9];
    const float* out_proj_w = (const float*)d_in[10];
    float* out = (float*)d_out;

    float* p = (float*)d_ws;
    float* zx    = p; p += (size_t)ROWS * DTOT;
    float* th_cs = p; p += (size_t)ROWS * 1024;   // dead after rot -> hseg
    float* Brot  = p; p += (size_t)ROWS * 2048;   // doubles as bf16 scratch
    float* Crot  = p; p += (size_t)ROWS * 2048;
    float* Bg    = p; p += (size_t)ROWS * 64;     // dead after rot -> aprod/bscale/Lbuf
    float* Cg    = p; p += (size_t)ROWS * 64;     // dead after rot -> wbuf
    float4* abg4 = (float4*)p; p += (size_t)ROWS * NH * 4;
    float* yb    = p; p += (size_t)ROWS * 2048;
    float* hseg   = th_cs;
    float* aprod  = Bg;
    float* bscale = Bg + 512;
    float* Lbuf   = Bg + 2048;
    float* wbuf   = Cg;

    u16* u_bf = (u16*)Brot;
    u16* u_lo = u_bf + (size_t)ROWS * DMODEL;
    u16* w_bf = u_lo + (size_t)ROWS * DMODEL;
    u16* w_lo = w_bf + (size_t)DTOT * DMODEL;
    u16* gn_bf = (u16*)Brot;
    u16* wo_bf = gn_bf + (size_t)ROWS * DIN;

    conv_uw<<<CONV_U_BLOCKS + CONV_W_BLOCKS, 256, 0, stream>>>(
        u, in_proj_w, u_bf, u_lo, w_bf, w_lo);
    mfma_inproj<<<ZX_BLOCKS + R3_BLOCKS, 256, 0, stream>>>(
        u_bf, u_lo, w_bf, w_lo, zx);
    prep_cumsum<<<512 + BB * NH, 256, 0, stream>>>(zx, dt_bias, A_log, B_norm_w,
                                                   C_norm_w, Bg, Cg, abg4, th_cs);
    rot_kernel<<<(ROWS * 1024) / 256, 256, 0, stream>>>(th_cs, Bg, Cg, B_bias, C_bias,
                                                        Brot, Crot);
    wcalc_kernel<<<BB * NH, 64, 0, stream>>>(abg4, wbuf, aprod, bscale, Lbuf);
    hseg_gemm<<<BB * NH * NSEG, 256, 0, stream>>>(zx, Brot, wbuf, hseg);
    scan_fix<<<BB * NH * 4, 256, 0, stream>>>(hseg, aprod, bscale, zx, Brot, abg4);
    ssd_y<<<BB * NH * NSEG, 256, 0, stream>>>(zx, Brot, Crot, abg4, hseg, Lbuf, Dp, yb);
    gate_convwo<<<ROWS + (DMODEL * DIN / 4) / 256, 256, 0, stream>>>(
        yb, zx, norm_w, gn_bf, out_proj_w, wo_bf);
    mfma_gemm_out<<<dim3(DMODEL / 64, ROWS / 128), 256, 0, stream>>>(
        gn_bf, wo_bf, out, DIN, DMODEL);
}